// Round 6
// baseline (260.800 us; speedup 1.0000x reference)
//
#include <hip/hip_runtime.h>

typedef unsigned short u16;
typedef unsigned int   u32;
typedef __attribute__((ext_vector_type(8))) short s8v;           // MFMA bf16 frag (8 bf16)
typedef __attribute__((ext_vector_type(8))) unsigned short us8;  // raw bf16x8 load
typedef __attribute__((ext_vector_type(4))) float f4v;           // MFMA acc frag

constexpr int BC  = 2;
constexpr int SL  = 4096;
constexpr int NH  = 12;
constexpr int HD  = 64;
constexpr int DM  = 768;
constexpr int WIN = 256;
constexpr int GLB = 64;
constexpr int QN  = 2304;   // q|k|v packed columns
constexpr int KCH = 32;     // global-attn key chunks (128 keys each)
constexpr float FOLD = 0.125f * 1.44269504088896f; // scale(1/sqrt(64)) * log2(e)
constexpr float NEGS = -1.0e9f;

__device__ __forceinline__ float b2f(u16 b){ return __uint_as_float(((u32)b) << 16); }
__device__ __forceinline__ u16 f2b(float f){
  u32 u = __float_as_uint(f);
  return (u16)((u + 0x7fffu + ((u >> 16) & 1u)) >> 16);  // RNE
}
__device__ __forceinline__ float wredsum(float v){
  #pragma unroll
  for (int o = 32; o > 0; o >>= 1) v += __shfl_xor(v, o, 64);
  return v;
}
__device__ __forceinline__ float sigf(float x){ return 1.f / (1.f + __expf(-x)); }

// ---------------------------------------------------------------- fused weight pack + embed gather
__global__ void pack_embed(const float* __restrict__ Wq, const float* __restrict__ Wk,
                           const float* __restrict__ Wv, const float* __restrict__ Wo,
                           const float* __restrict__ Wp,
                           const float* __restrict__ bq, const float* __restrict__ bk,
                           const float* __restrict__ bv,
                           u16* __restrict__ wt_qkv, u16* __restrict__ wt_o,
                           u16* __restrict__ wt_p, float* __restrict__ b_qkv,
                           const int* __restrict__ ids, const float* __restrict__ emb,
                           u16* __restrict__ xb)
{
  __shared__ float tile[64][65];
  const int bid = blockIdx.x;
  const int t = threadIdx.x;
  if (bid < 720){
    const int mi = bid / 144, rest = bid % 144;
    const int kt = rest / 12, ntc = rest % 12;
    const float* src = (mi==0)?Wq:(mi==1)?Wk:(mi==2)?Wv:(mi==3)?Wo:Wp;
    u16* dst = (mi<3) ? (wt_qkv + (size_t)mi*768*768) : ((mi==3) ? wt_o : wt_p);
    const int k0 = kt*64, n0 = ntc*64;
    #pragma unroll
    for (int i=0;i<4;i++){
      const int r = (t>>4) + i*16;
      float4 v = ((const float4*)(src + (long)(k0+r)*768 + n0))[t&15];
      tile[r][(t&15)*4+0] = v.x; tile[r][(t&15)*4+1] = v.y;
      tile[r][(t&15)*4+2] = v.z; tile[r][(t&15)*4+3] = v.w;
    }
    __syncthreads();
    const int n = t & 63, kc = (t>>6)*16;
    u32* d32 = (u32*)(dst + (long)(n0+n)*768 + k0 + kc);
    #pragma unroll
    for (int i=0;i<8;i++){
      d32[i] = (u32)f2b(tile[kc+2*i][n]) | ((u32)f2b(tile[kc+2*i+1][n]) << 16);
    }
    if (bid < 9){
      const int i = bid*256 + t;
      if (i < 2304) b_qkv[i] = (i < 768) ? bq[i] : (i < 1536) ? bk[i-768] : bv[i-1536];
    }
  } else {
    int e4 = (bid-720)*256 + t;                  // 8192 rows * 192 float4
    int row = e4 / 192, d4 = e4 - row*192;
    int id = ids[row];
    float4 v = ((const float4*)(emb + (long)id*768))[d4];
    u32 p0 = (u32)f2b(v.x) | ((u32)f2b(v.y) << 16);
    u32 p1 = (u32)f2b(v.z) | ((u32)f2b(v.w) << 16);
    ((u32*)(xb + (long)row*768))[d4*2]   = p0;
    ((u32*)(xb + (long)row*768))[d4*2+1] = p1;
  }
}

__global__ void gather_hr(const int* __restrict__ hidx, const float* __restrict__ hn,
                          u16* __restrict__ hrb){
  int e = blockIdx.x*256 + threadIdx.x;          // 512 rows * 768
  if (e >= 512*768) return;
  int r = e / 768, d = e - r*768;
  int b = r >> 8;
  int idx = hidx[r];
  hrb[e] = f2b(hn[((long)(b*SL + idx))*768 + d]);
}

// ---------------------------------------------------------------- bf16 MFMA GEMM
// MODE 0: outB = bf16(acc+bias)                 (qkv)
// MODE 1: outB = bf16(acc+bias+b2f(res))        (h = x + ctx@Wo + bo, bf16 everywhere)
// MODE 2: outB = bf16(relu(acc+bias))           (t)
// MODE 3: outF = sigmoid(acc)                   (cond, batched)
template<int MODE, bool SWZ>
__global__ __launch_bounds__(256, 2)
void gemm_bt(const u16* __restrict__ A, const u16* __restrict__ Bt,
             const float* __restrict__ bias, const u16* __restrict__ resB,
             float* __restrict__ outF, u16* __restrict__ outB,
             int M, int N, int K, long sA, long sB, long sO)
{
  const int bz = blockIdx.z;
  A  += (long)bz * sA;
  Bt += (long)bz * sB;
  int vid = blockIdx.x + gridDim.x*blockIdx.y;
  if constexpr (SWZ){
    const int chunk = (gridDim.x*gridDim.y) >> 3;
    vid = (vid & 7)*chunk + (vid >> 3);
  }
  const int n0 = (vid % gridDim.x) * 128;
  const int m0 = (vid / gridDim.x) * 128;
  __shared__ u16 lsA[128*64];
  __shared__ u16 lsB[128*64];
  const int t = threadIdx.x;
  const int w = t >> 6, lane = t & 63;
  const int wr = w >> 1, wc = w & 1;
  const int fr = lane & 15, fq = lane >> 4;

  f4v acc[4][4];
  #pragma unroll
  for (int i=0;i<4;i++)
    #pragma unroll
    for (int j=0;j<4;j++) acc[i][j] = (f4v)0.f;

  for (int k0 = 0; k0 < K; k0 += 64){
    #pragma unroll
    for (int i=0;i<4;i++){
      int e = (w*4+i)*512 + lane*8;
      int row = e >> 6, col = e & 63;
      __builtin_amdgcn_global_load_lds(
        (const __attribute__((address_space(1))) void*)(A + (long)(m0+row)*K + (k0+col)),
        (__attribute__((address_space(3))) void*)(&lsA[(w*4+i)*512]), 16, 0, 0);
      __builtin_amdgcn_global_load_lds(
        (const __attribute__((address_space(1))) void*)(Bt + (long)(n0+row)*K + (k0+col)),
        (__attribute__((address_space(3))) void*)(&lsB[(w*4+i)*512]), 16, 0, 0);
    }
    __syncthreads();
    #pragma unroll
    for (int kk = 0; kk < 2; kk++){
      s8v af[4], bfv[4];
      #pragma unroll
      for (int mi=0;mi<4;mi++)
        af[mi] = *(const s8v*)&lsA[(wr*64 + mi*16 + fr)*64 + kk*32 + fq*8];
      #pragma unroll
      for (int ni=0;ni<4;ni++)
        bfv[ni] = *(const s8v*)&lsB[(wc*64 + ni*16 + fr)*64 + kk*32 + fq*8];
      #pragma unroll
      for (int mi=0;mi<4;mi++)
        #pragma unroll
        for (int ni=0;ni<4;ni++)
          acc[mi][ni] = __builtin_amdgcn_mfma_f32_16x16x32_bf16(af[mi], bfv[ni], acc[mi][ni], 0, 0, 0);
    }
    __syncthreads();
  }
  #pragma unroll
  for (int mi=0;mi<4;mi++){
    #pragma unroll
    for (int ni=0;ni<4;ni++){
      #pragma unroll
      for (int r=0;r<4;r++){
        int row = m0 + wr*64 + mi*16 + fq*4 + r;
        int col = n0 + wc*64 + ni*16 + fr;
        float v = acc[mi][ni][r];
        if constexpr (MODE == 0){
          v += bias[col];
          outB[(long)row*N + col] = f2b(v);
        } else if constexpr (MODE == 1){
          v += bias[col] + b2f(resB[(long)row*N + col]);
          outB[(long)row*N + col] = f2b(v);
        } else if constexpr (MODE == 2){
          v = fmaxf(v + bias[col], 0.f);
          outB[(long)row*N + col] = f2b(v);
        } else {
          (outF + bz*sO)[(long)row*N + col] = sigf(v);
        }
      }
    }
  }
}

// ---------------------------------------------------------------- fused attention (band + global-row partials)
// Grid (96, H, B), 256 thr, bijective XCD swizzle over x.
//   vid <  64: banded flash for q-tile vid (QBLK=64, 4 waves x 16 q, 2-phase pipeline)
//   vid >= 64: global-row partials for 128-key chunk ck=vid-64 (2 tiles)
// Pipeline hazard proof (both paths): one barrier per tile; stage(i+1) issued after
// barrier(i); buffer p written at iter i+2 was last read in compute(i), separated by
// barrier(i+1). __syncthreads drains vmcnt(0) so K-DMA(i) is complete before compute(i).
__global__ __launch_bounds__(256, 3)
void attn_fused(const u16* __restrict__ qkv, const float* __restrict__ mask,
                u16* __restrict__ ctx, float* __restrict__ pout, float* __restrict__ pml)
{
  const int bx = blockIdx.x;
  const int vid = (bx & 7)*12 + (bx >> 3);              // 96 = 8 XCD chunks of 12
  const int h = blockIdx.y, b = blockIdx.z;
  const int t = threadIdx.x;
  const int w = t >> 6, lane = t & 63;
  const int fq = lane >> 4, fr = lane & 15;

  __shared__ u16 lsK[2][64*64];    // row r: 16B chunk c8 holds K[r][(c8^(r&7))*8 ..+8)
  __shared__ u16 lsVT[2][64*72];   // V^T[d][k], row stride 72
  __shared__ u16 lsP[4][16*72];    // per-wave P
  __shared__ float lsM[2][64];

  const long bq = (long)b*SL*QN;
  const u16* kq = qkv + bq + DM + h*HD;
  const u16* vq = qkv + bq + 2*DM + h*HD;
  const float* mrow = mask + b*SL;

  f4v out[4];
  #pragma unroll
  for (int n=0;n<4;n++) out[n] = (f4v)0.f;
  float m[4]  = {-3.0e38f,-3.0e38f,-3.0e38f,-3.0e38f};
  float l[4]  = {0.f,0.f,0.f,0.f};

  us8 vv0, vv1;

  if (vid < 64){
    // ===================== banded path =====================
    const int q0 = vid * 64;
    const u16* qrow = qkv + (bq + (long)(q0 + w*16 + fr)*QN) + h*HD;
    s8v aq[2];
    aq[0] = *(const s8v*)(qrow + fq*8);
    aq[1] = *(const s8v*)(qrow + 32 + fq*8);

    // tile 0 = global keys [0,64); tiles ti in [ti_lo, ti_hi) at k0 = q0-256+ti*64
    const int ti_lo = (q0 < 320) ? ((320 - q0) >> 6) : 0;
    const int ti_hi_raw = (4352 - q0) >> 6;
    const int ti_hi = ti_hi_raw < 9 ? ti_hi_raw : 9;
    const int NTT = 1 + (ti_hi - ti_lo);
    const int kb0 = q0 - 256 + ti_lo*64;

    auto stage_issue = [&](int i, int buf){
      const int k0 = (i == 0) ? 0 : kb0 + (i-1)*64;
      if (t < 64) lsM[buf][t] = mrow[k0 + t];
      #pragma unroll
      for (int j=0;j<2;j++){
        const int r = (w*2+j)*8 + (lane>>3);
        const int d = ((lane&7) ^ (lane>>3))*8;          // pre-swizzled source col
        __builtin_amdgcn_global_load_lds(
          (const __attribute__((address_space(1))) void*)(kq + (long)(k0+r)*QN + d),
          (__attribute__((address_space(3))) void*)(&lsK[buf][(w*2+j)*512]), 16, 0, 0);
      }
      vv0 = *(const us8*)(vq + (long)(k0+lane)*QN + w*8);
      vv1 = *(const us8*)(vq + (long)(k0+lane)*QN + w*8 + 32);
    };

    stage_issue(0, 0);
    int cur = 0;
    for (int i = 0; i < NTT; i++){
      const int k0 = (i == 0) ? 0 : kb0 + (i-1)*64;
      const int d0 = w*8;
      #pragma unroll
      for (int jj=0;jj<8;jj++) lsVT[cur][(d0+jj)*72 + lane] = (u16)vv0[jj];
      #pragma unroll
      for (int jj=0;jj<8;jj++) lsVT[cur][(d0+32+jj)*72 + lane] = (u16)vv1[jj];
      __syncthreads();
      if (i+1 < NTT) stage_issue(i+1, cur^1);

      f4v s[4];
      #pragma unroll
      for (int n=0;n<4;n++) s[n] = (f4v)0.f;
      __builtin_amdgcn_s_setprio(1);
      #pragma unroll
      for (int kk=0;kk<2;kk++){
        #pragma unroll
        for (int n=0;n<4;n++){
          s8v bf = *(const s8v*)&lsK[cur][(16*n+fr)*64 + (((kk*4+fq) ^ (fr&7))<<3)];
          s[n] = __builtin_amdgcn_mfma_f32_16x16x32_bf16(aq[kk], bf, s[n], 0,0,0);
        }
      }
      __builtin_amdgcn_s_setprio(0);
      const bool isg = (i == 0);
      #pragma unroll
      for (int n=0;n<4;n++){
        const int kcol = 16*n + fr;
        const float mk = lsM[cur][kcol];
        #pragma unroll
        for (int r=0;r<4;r++){
          const int dd = k0 + kcol - (q0 + w*16 + fq*4 + r);
          const bool valid = (mk > 0.f) && (isg || (dd >= -WIN && dd <= WIN));
          s[n][r] = valid ? s[n][r]*FOLD : NEGS;
        }
      }
      // defer-max (T13): skip O-rescale unless max grew > 8
      float rm[4];
      #pragma unroll
      for (int r=0;r<4;r++){
        float v = fmaxf(fmaxf(s[0][r], s[1][r]), fmaxf(s[2][r], s[3][r]));
        v = fmaxf(v, __shfl_xor(v, 1, 64));
        v = fmaxf(v, __shfl_xor(v, 2, 64));
        v = fmaxf(v, __shfl_xor(v, 4, 64));
        v = fmaxf(v, __shfl_xor(v, 8, 64));
        rm[r] = v;
      }
      bool need = false;
      #pragma unroll
      for (int r=0;r<4;r++) need |= (rm[r] > m[r] + 8.f);
      if (__any(need)){
        #pragma unroll
        for (int r=0;r<4;r++){
          const float mn = fmaxf(m[r], rm[r]);
          const float sf = exp2f(m[r] - mn);
          m[r] = mn;
          l[r] *= sf;
          #pragma unroll
          for (int n=0;n<4;n++) out[n][r] *= sf;
        }
      }
      u16* lsPw = lsP[w];
      float rs[4] = {0.f,0.f,0.f,0.f};
      #pragma unroll
      for (int n=0;n<4;n++){
        #pragma unroll
        for (int r=0;r<4;r++){
          float p = exp2f(s[n][r] - m[r]);
          rs[r] += p;
          lsPw[(fq*4+r)*72 + 16*n + fr] = f2b(p);
        }
      }
      #pragma unroll
      for (int r=0;r<4;r++){
        float rv = rs[r];
        rv += __shfl_xor(rv, 1, 64);
        rv += __shfl_xor(rv, 2, 64);
        rv += __shfl_xor(rv, 4, 64);
        rv += __shfl_xor(rv, 8, 64);
        l[r] += rv;
      }
      s8v ap[2];
      ap[0] = *(const s8v*)&lsPw[fr*72 + fq*8];
      ap[1] = *(const s8v*)&lsPw[fr*72 + 32 + fq*8];
      __builtin_amdgcn_s_setprio(1);
      #pragma unroll
      for (int kk=0;kk<2;kk++){
        #pragma unroll
        for (int n=0;n<4;n++){
          s8v bv = *(const s8v*)&lsVT[cur][(16*n+fr)*72 + kk*32 + fq*8];
          out[n] = __builtin_amdgcn_mfma_f32_16x16x32_bf16(ap[kk], bv, out[n], 0,0,0);
        }
      }
      __builtin_amdgcn_s_setprio(0);
      cur ^= 1;
    }
    #pragma unroll
    for (int r=0;r<4;r++) l[r] = 1.f/l[r];
    u16* cb = ctx + (((long)(b*SL) + q0 + w*16 + fq*4))*DM + h*HD + fr;
    #pragma unroll
    for (int n=0;n<4;n++)
      #pragma unroll
      for (int r=0;r<4;r++)
        cb[(long)r*DM + 16*n] = f2b(out[n][r]*l[r]);

  } else {
    // ===================== global-row partials path =====================
    const int ck = vid - 64;
    const int bh = b*NH + h;
    const u16* qrow = qkv + (bq + (long)(w*16 + fr)*QN) + h*HD;   // q rows 0..63
    s8v aq[2];
    aq[0] = *(const s8v*)(qrow + fq*8);
    aq[1] = *(const s8v*)(qrow + 32 + fq*8);

    auto stage_issue = [&](int i, int buf){
      const int k0 = ck*128 + i*64;
      if (t < 64) lsM[buf][t] = mrow[k0 + t];
      #pragma unroll
      for (int j=0;j<2;j++){
        const int r = (w*2+j)*8 + (lane>>3);
        const int d = ((lane&7) ^ (lane>>3))*8;
        __builtin_amdgcn_global_load_lds(
          (const __attribute__((address_space(1))) void*)(kq + (long)(k0+r)*QN + d),
          (__attribute__((address_space(3))) void*)(&lsK[buf][(w*2+j)*512]), 16, 0, 0);
      }
      vv0 = *(const us8*)(vq + (long)(k0+lane)*QN + w*8);
      vv1 = *(const us8*)(vq + (long)(k0+lane)*QN + w*8 + 32);
    };

    stage_issue(0, 0);
    int cur = 0;
    for (int i = 0; i < 2; i++){
      const int d0 = w*8;
      #pragma unroll
      for (int jj=0;jj<8;jj++) lsVT[cur][(d0+jj)*72 + lane] = (u16)vv0[jj];
      #pragma unroll
      for (int jj=0;jj<8;jj++) lsVT[cur][(d0+32+jj)*72 + lane] = (u16)vv1[jj];
      __syncthreads();
      if (i+1 < 2) stage_issue(i+1, cur^1);

      f4v s[4];
      #pragma unroll
      for (int n=0;n<4;n++) s[n] = (f4v)0.f;
      __builtin_amdgcn_s_setprio(1);
      #pragma unroll
      for (int kk=0;kk<2;kk++){
        #pragma unroll
        for (int n=0;n<4;n++){
          s8v bf = *(const s8v*)&lsK[cur][(16*n+fr)*64 + (((kk*4+fq) ^ (fr&7))<<3)];
          s[n] = __builtin_amdgcn_mfma_f32_16x16x32_bf16(aq[kk], bf, s[n], 0,0,0);
        }
      }
      __builtin_amdgcn_s_setprio(0);
      #pragma unroll
      for (int n=0;n<4;n++){
        const float mk = lsM[cur][16*n + fr];
        #pragma unroll
        for (int r=0;r<4;r++)
          s[n][r] = (mk > 0.f) ? s[n][r]*FOLD : NEGS;
      }
      float sf[4];
      #pragma unroll
      for (int r=0;r<4;r++){
        float rm = fmaxf(fmaxf(s[0][r], s[1][r]), fmaxf(s[2][r], s[3][r]));
        rm = fmaxf(rm, __shfl_xor(rm, 1, 64));
        rm = fmaxf(rm, __shfl_xor(rm, 2, 64));
        rm = fmaxf(rm, __shfl_xor(rm, 4, 64));
        rm = fmaxf(rm, __shfl_xor(rm, 8, 64));
        const float mn = fmaxf(m[r], rm);
        sf[r] = exp2f(m[r] - mn);
        m[r] = mn;
      }
      u16* lsPw = lsP[w];
      float rs[4] = {0.f,0.f,0.f,0.f};
      #pragma unroll
      for (int n=0;n<4;n++){
        #pragma unroll
        for (int r=0;r<4;r++){
          float p = exp2f(s[n][r] - m[r]);
          rs[r] += p;
          lsPw[(fq*4+r)*72 + 16*n + fr] = f2b(p);
          out[n][r] *= sf[r];
        }
      }
      #pragma unroll
      for (int r=0;r<4;r++){
        float rv = rs[r];
        rv += __shfl_xor(rv, 1, 64);
        rv += __shfl_xor(rv, 2, 64);
        rv += __shfl_xor(rv, 4, 64);
        rv += __shfl_xor(rv, 8, 64);
        l[r] = l[r]*sf[r] + rv;
      }
      s8v ap[2];
      ap[0] = *(const s8v*)&lsPw[fr*72 + fq*8];
      ap[1] = *(const s8v*)&lsPw[fr*72 + 32 + fq*8];
      __builtin_amdgcn_s_setprio(1);
      #pragma unroll
      for (int kk=0;kk<2;kk++){
        #pragma unroll
        for (int n=0;n<4;n++){
          s8v bv = *(const s8v*)&lsVT[cur][(16*n+fr)*72 + kk*32 + fq*8];
          out[n] = __builtin_amdgcn_mfma_f32_16x16x32_bf16(ap[kk], bv, out[n], 0,0,0);
        }
      }
      __builtin_amdgcn_s_setprio(0);
      cur ^= 1;
    }
    float* pob = pout + ((long)(ck*BC*NH + bh))*64*64;
    #pragma unroll
    for (int n=0;n<4;n++)
      #pragma unroll
      for (int r=0;r<4;r++)
        pob[(w*16 + fq*4 + r)*64 + 16*n + fr] = out[n][r];
    if (fr == 0){
      float* pmb = pml + ((long)(ck*BC*NH + bh))*128;
      #pragma unroll
      for (int r=0;r<4;r++){
        pmb[(w*16 + fq*4 + r)*2 + 0] = m[r];
        pmb[(w*16 + fq*4 + r)*2 + 1] = l[r];
      }
    }
  }
}

__global__ __launch_bounds__(256, 2)
void attn_global_combine(const float* __restrict__ pout, const float* __restrict__ pml,
                         u16* __restrict__ ctx)
{
  const int bh = blockIdx.x;
  const int b = bh / NH, h = bh % NH;
  const int t = threadIdx.x;
  __shared__ float wgt[KCH][64];
  __shared__ float rl[64];
  if (t < 64){
    float mc[KCH], lc[KCH];
    #pragma unroll
    for (int c = 0; c < KCH; c++){
      const float* pmb = pml + ((long)(c*BC*NH + bh))*128 + t*2;
      mc[c] = pmb[0]; lc[c] = pmb[1];
    }
    float M = mc[0];
    #pragma unroll
    for (int c = 1; c < KCH; c++) M = fmaxf(M, mc[c]);
    float L = 0.f;
    #pragma unroll
    for (int c = 0; c < KCH; c++){
      const float wv = exp2f(mc[c] - M);
      wgt[c][t] = wv;
      L += lc[c]*wv;
    }
    rl[t] = 1.f/L;
  }
  __syncthreads();
  const int row = t >> 2, dseg = t & 3;
  float acc[16];
  #pragma unroll
  for (int i=0;i<16;i++) acc[i] = 0.f;
  for (int c = 0; c < KCH; c++){
    const float wv = wgt[c][row];
    const float4* pb = (const float4*)(pout + ((long)(c*BC*NH + bh)*64 + row)*64 + dseg*16);
    #pragma unroll
    for (int i = 0; i < 4; i++){
      float4 v = pb[i];
      acc[i*4+0] += v.x*wv; acc[i*4+1] += v.y*wv;
      acc[i*4+2] += v.z*wv; acc[i*4+3] += v.w*wv;
    }
  }
  u16* cr = ctx + ((long)(b*SL + row))*DM + h*HD + dseg*16;
  const float r = rl[row];
  #pragma unroll
  for (int i = 0; i < 16; i += 2){
    u32 pk = (u32)f2b(acc[i]*r) | ((u32)f2b(acc[i+1]*r) << 16);
    *(u32*)(cr + i) = pk;
  }
}

// ---------------------------------------------------------------- LayerNorm + ans/span heads (bf16 h input)
// 384 threads: thread t owns columns 2t, 2t+1 (one u32 = 2 bf16).
__global__ __launch_bounds__(384, 2)
void ln_heads(const u16* __restrict__ hb, const float* __restrict__ gamma, const float* __restrict__ beta,
              const float* __restrict__ Wa, const float* __restrict__ ba,
              const float* __restrict__ Wsp, const float* __restrict__ bsp,
              float* __restrict__ hn, float* __restrict__ ans, float* __restrict__ span)
{
  const int r = blockIdx.x;
  const int t = threadIdx.x, lane = t & 63, w = t >> 6;   // w in 0..5
  __shared__ float red[12];
  __shared__ float dred[6][5];
  const u32 pk = ((const u32*)(hb + (long)r*DM))[t];
  const float v0 = b2f((u16)(pk & 0xffff));
  const float v1 = b2f((u16)(pk >> 16));
  float sum = wredsum(v0 + v1);
  float sq  = wredsum(v0*v0 + v1*v1);
  if (lane == 0){ red[w] = sum; red[6+w] = sq; }
  __syncthreads();
  float mu = 0.f, msq = 0.f;
  #pragma unroll
  for (int i=0;i<6;i++){ mu += red[i]; msq += red[6+i]; }
  mu *= (1.f/768.f); msq *= (1.f/768.f);
  const float rstd = rsqrtf(msq - mu*mu + 1e-5f);
  const int i0 = 2*t, i1 = 2*t+1;
  const float y0 = (v0 - mu)*rstd*gamma[i0] + beta[i0];
  const float y1 = (v1 - mu)*rstd*gamma[i1] + beta[i1];
  ((float2*)(hn + (long)r*DM))[t] = make_float2(y0, y1);
  float pa0 = y0*Wa[i0*3+0] + y1*Wa[i1*3+0];
  float pa1 = y0*Wa[i0*3+1] + y1*Wa[i1*3+1];
  float pa2 = y0*Wa[i0*3+2] + y1*Wa[i1*3+2];
  float ps0 = y0*Wsp[i0*2+0] + y1*Wsp[i1*2+0];
  float ps1 = y0*Wsp[i0*2+1] + y1*Wsp[i1*2+1];
  pa0 = wredsum(pa0); pa1 = wredsum(pa1); pa2 = wredsum(pa2);
  ps0 = wredsum(ps0); ps1 = wredsum(ps1);
  if (lane == 0){ dred[w][0]=pa0; dred[w][1]=pa1; dred[w][2]=pa2; dred[w][3]=ps0; dred[w][4]=ps1; }
  __syncthreads();
  if (t == 0){
    float A0=0,A1=0,A2=0,S0=0,S1=0;
    #pragma unroll
    for (int i=0;i<6;i++){ A0+=dred[i][0]; A1+=dred[i][1]; A2+=dred[i][2]; S0+=dred[i][3]; S1+=dred[i][4]; }
    ans[(long)r*3+0]  = sigf(A0 + ba[0]);
    ans[(long)r*3+1]  = sigf(A1 + ba[1]);
    ans[(long)r*3+2]  = sigf(A2 + ba[2]);
    span[(long)r*2+0] = sigf(S0 + bsp[0]);
    span[(long)r*2+1] = sigf(S1 + bsp[1]);
  }
}

// ---------------------------------------------------------------- launch
extern "C" void kernel_launch(void* const* d_in, const int* in_sizes, int n_in,
                              void* d_out, int out_size, void* d_ws, size_t ws_size,
                              hipStream_t stream)
{
  const int*   input_ids = (const int*)  d_in[0];
  const float* attn_mask = (const float*)d_in[1];
  const int*   html_idx  = (const int*)  d_in[2];
  const float* embed     = (const float*)d_in[3];
  const float* Wq = (const float*)d_in[4];  const float* bq = (const float*)d_in[5];
  const float* Wk = (const float*)d_in[6];  const float* bk = (const float*)d_in[7];
  const float* Wv = (const float*)d_in[8];  const float* bv = (const float*)d_in[9];
  const float* Wo = (const float*)d_in[10]; const float* bo = (const float*)d_in[11];
  const float* gamma = (const float*)d_in[12]; const float* beta = (const float*)d_in[13];
  const float* Wp = (const float*)d_in[14]; const float* bp = (const float*)d_in[15];
  const float* Wa = (const float*)d_in[16]; const float* ba = (const float*)d_in[17];
  const float* Wsp = (const float*)d_in[18]; const float* bsp = (const float*)d_in[19];

  char* ws = (char*)d_ws;
  size_t off = 0;
  auto take = [&](size_t bytes)->char*{
    char* p = ws + off; off += (bytes + 255) & ~(size_t)255; return p;
  };
  u16*   x_b    = (u16*)  take((size_t)8192*768*2);
  u16*   wt_qkv = (u16*)  take((size_t)2304*768*2);
  u16*   wt_o   = (u16*)  take((size_t)768*768*2);
  u16*   wt_p   = (u16*)  take((size_t)768*768*2);
  float* b_qkv  = (float*)take(2304*4);
  u16*   qkv_b  = (u16*)  take((size_t)8192*2304*2);
  u16*   ctx_b  = (u16*)  take((size_t)8192*768*2);
  u16*   h_b    = (u16*)  take((size_t)8192*768*2);
  u16*   hr_b   = (u16*)  take((size_t)512*768*2);
  u16*   t_b    = (u16*)  take((size_t)512*768*2);
  float* pout   = (float*)take((size_t)KCH*BC*NH*64*64*4);
  float* pml    = (float*)take((size_t)KCH*BC*NH*128*4);

  float* out_hn   = (float*)d_out;
  float* out_ans  = out_hn  + (size_t)8192*768;
  float* out_span = out_ans + (size_t)8192*3;
  float* out_cond = out_span + (size_t)8192*2;

  pack_embed<<<6864, 256, 0, stream>>>(Wq, Wk, Wv, Wo, Wp, bq, bk, bv,
                                       wt_qkv, wt_o, wt_p, b_qkv,
                                       input_ids, embed, x_b);

  gemm_bt<0,true><<<dim3(18,64,1), 256, 0, stream>>>(x_b, wt_qkv, b_qkv, nullptr,
                                                nullptr, qkv_b, 8192, 2304, 768, 0,0,0);
  attn_fused<<<dim3(96,12,2), 256, 0, stream>>>(qkv_b, attn_mask, ctx_b, pout, pml);
  attn_global_combine<<<BC*NH, 256, 0, stream>>>(pout, pml, ctx_b);
  gemm_bt<1,true><<<dim3(6,64,1), 256, 0, stream>>>(ctx_b, wt_o, bo, x_b,
                                               nullptr, h_b, 8192, 768, 768, 0,0,0);
  ln_heads<<<8192, 384, 0, stream>>>(h_b, gamma, beta, Wa, ba, Wsp, bsp,
                                     out_hn, out_ans, out_span);
  gather_hr<<<1536, 256, 0, stream>>>(html_idx, out_hn, hr_b);
  gemm_bt<2,false><<<dim3(6,4,1), 256, 0, stream>>>(hr_b, wt_p, bp, nullptr,
                                              nullptr, t_b, 512, 768, 768, 0,0,0);
  gemm_bt<3,false><<<dim3(2,2,2), 256, 0, stream>>>(t_b, hr_b, nullptr, nullptr,
                                              out_cond, nullptr, 256, 256, 768,
                                              (long)256*768, (long)256*768, (long)256*256);
}

// Round 7
// 229.152 us; speedup vs baseline: 1.1381x; 1.1381x over previous
//
#include <hip/hip_runtime.h>

typedef unsigned short u16;
typedef unsigned int   u32;
typedef __attribute__((ext_vector_type(8))) short s8v;           // MFMA bf16 frag (8 bf16)
typedef __attribute__((ext_vector_type(8))) unsigned short us8;  // raw bf16x8 load
typedef __attribute__((ext_vector_type(4))) float f4v;           // MFMA acc frag

constexpr int BC  = 2;
constexpr int SL  = 4096;
constexpr int NH  = 12;
constexpr int HD  = 64;
constexpr int DM  = 768;
constexpr int WIN = 256;
constexpr int GLB = 64;
constexpr int QN  = 2304;   // q|k|v packed columns
constexpr int KCH = 32;     // global-attn key chunks (128 keys each)
constexpr float FOLD = 0.125f * 1.44269504088896f; // scale(1/sqrt(64)) * log2(e)
constexpr float NEGS = -1.0e9f;
constexpr float DEFER = 44.36f;                    // 8 / FOLD (defer-max threshold, raw units)

__device__ __forceinline__ float b2f(u16 b){ return __uint_as_float(((u32)b) << 16); }
__device__ __forceinline__ u16 f2b(float f){
  u32 u = __float_as_uint(f);
  return (u16)((u + 0x7fffu + ((u >> 16) & 1u)) >> 16);  // RNE
}
__device__ __forceinline__ float wredsum(float v){
  #pragma unroll
  for (int o = 32; o > 0; o >>= 1) v += __shfl_xor(v, o, 64);
  return v;
}
__device__ __forceinline__ float sigf(float x){ return 1.f / (1.f + __expf(-x)); }

// ---------------------------------------------------------------- fused weight pack + embed gather
__global__ void pack_embed(const float* __restrict__ Wq, const float* __restrict__ Wk,
                           const float* __restrict__ Wv, const float* __restrict__ Wo,
                           const float* __restrict__ Wp,
                           const float* __restrict__ bq, const float* __restrict__ bk,
                           const float* __restrict__ bv,
                           u16* __restrict__ wt_qkv, u16* __restrict__ wt_o,
                           u16* __restrict__ wt_p, float* __restrict__ b_qkv,
                           const int* __restrict__ ids, const float* __restrict__ emb,
                           u16* __restrict__ xb)
{
  __shared__ float tile[64][65];
  const int bid = blockIdx.x;
  const int t = threadIdx.x;
  if (bid < 720){
    const int mi = bid / 144, rest = bid % 144;
    const int kt = rest / 12, ntc = rest % 12;
    const float* src = (mi==0)?Wq:(mi==1)?Wk:(mi==2)?Wv:(mi==3)?Wo:Wp;
    u16* dst = (mi<3) ? (wt_qkv + (size_t)mi*768*768) : ((mi==3) ? wt_o : wt_p);
    const int k0 = kt*64, n0 = ntc*64;
    #pragma unroll
    for (int i=0;i<4;i++){
      const int r = (t>>4) + i*16;
      float4 v = ((const float4*)(src + (long)(k0+r)*768 + n0))[t&15];
      tile[r][(t&15)*4+0] = v.x; tile[r][(t&15)*4+1] = v.y;
      tile[r][(t&15)*4+2] = v.z; tile[r][(t&15)*4+3] = v.w;
    }
    __syncthreads();
    const int n = t & 63, kc = (t>>6)*16;
    u32* d32 = (u32*)(dst + (long)(n0+n)*768 + k0 + kc);
    #pragma unroll
    for (int i=0;i<8;i++){
      d32[i] = (u32)f2b(tile[kc+2*i][n]) | ((u32)f2b(tile[kc+2*i+1][n]) << 16);
    }
    if (bid < 9){
      const int i = bid*256 + t;
      if (i < 2304) b_qkv[i] = (i < 768) ? bq[i] : (i < 1536) ? bk[i-768] : bv[i-1536];
    }
  } else {
    int e4 = (bid-720)*256 + t;                  // 8192 rows * 192 float4
    int row = e4 / 192, d4 = e4 - row*192;
    int id = ids[row];
    float4 v = ((const float4*)(emb + (long)id*768))[d4];
    u32 p0 = (u32)f2b(v.x) | ((u32)f2b(v.y) << 16);
    u32 p1 = (u32)f2b(v.z) | ((u32)f2b(v.w) << 16);
    ((u32*)(xb + (long)row*768))[d4*2]   = p0;
    ((u32*)(xb + (long)row*768))[d4*2+1] = p1;
  }
}

__global__ void gather_hr(const int* __restrict__ hidx, const float* __restrict__ hn,
                          u16* __restrict__ hrb){
  int e = blockIdx.x*256 + threadIdx.x;          // 512 rows * 768
  if (e >= 512*768) return;
  int r = e / 768, d = e - r*768;
  int b = r >> 8;
  int idx = hidx[r];
  hrb[e] = f2b(hn[((long)(b*SL + idx))*768 + d]);
}

// ---------------------------------------------------------------- bf16 MFMA GEMM
// MODE 0: outB = bf16(acc+bias)                 (qkv)
// MODE 1: outB = bf16(acc+bias+b2f(res))        (h = x + ctx@Wo + bo)
// MODE 2: outB = bf16(relu(acc+bias))           (t)
// MODE 3: outF = sigmoid(acc)                   (cond, batched)
template<int MODE, bool SWZ>
__global__ __launch_bounds__(256, 2)
void gemm_bt(const u16* __restrict__ A, const u16* __restrict__ Bt,
             const float* __restrict__ bias, const u16* __restrict__ resB,
             float* __restrict__ outF, u16* __restrict__ outB,
             int M, int N, int K, long sA, long sB, long sO)
{
  const int bz = blockIdx.z;
  A  += (long)bz * sA;
  Bt += (long)bz * sB;
  int vid = blockIdx.x + gridDim.x*blockIdx.y;
  if constexpr (SWZ){
    const int chunk = (gridDim.x*gridDim.y) >> 3;
    vid = (vid & 7)*chunk + (vid >> 3);
  }
  const int n0 = (vid % gridDim.x) * 128;
  const int m0 = (vid / gridDim.x) * 128;
  __shared__ u16 lsA[128*64];
  __shared__ u16 lsB[128*64];
  const int t = threadIdx.x;
  const int w = t >> 6, lane = t & 63;
  const int wr = w >> 1, wc = w & 1;
  const int fr = lane & 15, fq = lane >> 4;

  f4v acc[4][4];
  #pragma unroll
  for (int i=0;i<4;i++)
    #pragma unroll
    for (int j=0;j<4;j++) acc[i][j] = (f4v)0.f;

  for (int k0 = 0; k0 < K; k0 += 64){
    #pragma unroll
    for (int i=0;i<4;i++){
      int e = (w*4+i)*512 + lane*8;
      int row = e >> 6, col = e & 63;
      __builtin_amdgcn_global_load_lds(
        (const __attribute__((address_space(1))) void*)(A + (long)(m0+row)*K + (k0+col)),
        (__attribute__((address_space(3))) void*)(&lsA[(w*4+i)*512]), 16, 0, 0);
      __builtin_amdgcn_global_load_lds(
        (const __attribute__((address_space(1))) void*)(Bt + (long)(n0+row)*K + (k0+col)),
        (__attribute__((address_space(3))) void*)(&lsB[(w*4+i)*512]), 16, 0, 0);
    }
    __syncthreads();
    #pragma unroll
    for (int kk = 0; kk < 2; kk++){
      s8v af[4], bfv[4];
      #pragma unroll
      for (int mi=0;mi<4;mi++)
        af[mi] = *(const s8v*)&lsA[(wr*64 + mi*16 + fr)*64 + kk*32 + fq*8];
      #pragma unroll
      for (int ni=0;ni<4;ni++)
        bfv[ni] = *(const s8v*)&lsB[(wc*64 + ni*16 + fr)*64 + kk*32 + fq*8];
      #pragma unroll
      for (int mi=0;mi<4;mi++)
        #pragma unroll
        for (int ni=0;ni<4;ni++)
          acc[mi][ni] = __builtin_amdgcn_mfma_f32_16x16x32_bf16(af[mi], bfv[ni], acc[mi][ni], 0, 0, 0);
    }
    __syncthreads();
  }
  #pragma unroll
  for (int mi=0;mi<4;mi++){
    #pragma unroll
    for (int ni=0;ni<4;ni++){
      #pragma unroll
      for (int r=0;r<4;r++){
        int row = m0 + wr*64 + mi*16 + fq*4 + r;
        int col = n0 + wc*64 + ni*16 + fr;
        float v = acc[mi][ni][r];
        if constexpr (MODE == 0){
          v += bias[col];
          outB[(long)row*N + col] = f2b(v);
        } else if constexpr (MODE == 1){
          v += bias[col] + b2f(resB[(long)row*N + col]);
          outB[(long)row*N + col] = f2b(v);
        } else if constexpr (MODE == 2){
          v = fmaxf(v + bias[col], 0.f);
          outB[(long)row*N + col] = f2b(v);
        } else {
          (outF + bz*sO)[(long)row*N + col] = sigf(v);
        }
      }
    }
  }
}

// ---------------------------------------------------------------- banded attention, MFMA flash
// QBLK=64, 4 waves x 16 q rows, 2-phase pipelined (R4-proven hazard structure:
// one barrier per tile; stage(i+1) after barrier(i); writes at i+2 separated from
// reads at i by barrier(i+1); __syncthreads drains vmcnt so K-DMA(i) is complete).
// Softmax-lite: single running max per fq-group (exact: same m in num+denom);
// l computed by MFMA via ones-row 64 of V^T (out[4], fr==0 column = sum_k P);
// wave-uniform full-valid fast path; P->bf16 via v_cvt_pk_bf16_f32.
__global__ __launch_bounds__(256, 3)
void attn_band_mfma(const u16* __restrict__ qkv, const float* __restrict__ mask, u16* __restrict__ ctx)
{
  const int q0 = blockIdx.x * 64;
  const int h = blockIdx.y, b = blockIdx.z;
  const int t = threadIdx.x;
  const int w = t >> 6, lane = t & 63;
  const int fq = lane >> 4, fr = lane & 15;

  __shared__ u16 lsK[2][64*64];    // row r: 16B chunk c8 holds K[r][(c8^(r&7))*8 ..+8)
  __shared__ u16 lsVT[2][80*72];   // V^T[d][k] rows 0..63; row 64 = ones, 65..79 = 0
  __shared__ u16 lsP[4][16*72];    // per-wave P
  __shared__ float lsM[2][64];

  // ones/zero rows (written once; V staging only touches rows 0..63)
  for (int e = t; e < 16*72; e += 256){
    const u16 v = (e < 72) ? (u16)0x3F80 : (u16)0;
    lsVT[0][64*72 + e] = v;
    lsVT[1][64*72 + e] = v;
  }

  const long bq = (long)b*SL*QN;
  const u16* qrow = qkv + (bq + (long)(q0 + w*16 + fr)*QN) + h*HD;
  s8v aq[2];
  aq[0] = *(const s8v*)(qrow + fq*8);
  aq[1] = *(const s8v*)(qrow + 32 + fq*8);

  const u16* kq = qkv + bq + DM + h*HD;
  const u16* vq = qkv + bq + 2*DM + h*HD;
  const float* mrow = mask + b*SL;

  // tile 0 = global keys [0,64); band tiles ti in [ti_lo, ti_hi) at k0 = q0-256+ti*64
  const int ti_lo = (q0 < 320) ? ((320 - q0) >> 6) : 0;
  const int ti_hi_raw = (4352 - q0) >> 6;
  const int ti_hi = ti_hi_raw < 9 ? ti_hi_raw : 9;
  const int NTT = 1 + (ti_hi - ti_lo);
  const int kb0 = q0 - 256 + ti_lo*64;

  f4v out[5];
  #pragma unroll
  for (int n=0;n<5;n++) out[n] = (f4v)0.f;
  float m = -3.0e38f;                 // raw-score units, shared by the 4 rows of this fq group

  us8 vv0, vv1;
  auto stage_issue = [&](int i, int buf){
    const int k0 = (i == 0) ? 0 : kb0 + (i-1)*64;
    if (t < 64) lsM[buf][t] = mrow[k0 + t];
    #pragma unroll
    for (int j=0;j<2;j++){
      const int r = (w*2+j)*8 + (lane>>3);
      const int d = ((lane&7) ^ (lane>>3))*8;          // pre-swizzled source col
      __builtin_amdgcn_global_load_lds(
        (const __attribute__((address_space(1))) void*)(kq + (long)(k0+r)*QN + d),
        (__attribute__((address_space(3))) void*)(&lsK[buf][(w*2+j)*512]), 16, 0, 0);
    }
    vv0 = *(const us8*)(vq + (long)(k0+lane)*QN + w*8);
    vv1 = *(const us8*)(vq + (long)(k0+lane)*QN + w*8 + 32);
  };

  stage_issue(0, 0);
  int cur = 0;
  for (int i = 0; i < NTT; i++){
    const int k0 = (i == 0) ? 0 : kb0 + (i-1)*64;
    const int d0 = w*8;
    #pragma unroll
    for (int jj=0;jj<8;jj++) lsVT[cur][(d0+jj)*72 + lane] = (u16)vv0[jj];
    #pragma unroll
    for (int jj=0;jj<8;jj++) lsVT[cur][(d0+32+jj)*72 + lane] = (u16)vv1[jj];
    __syncthreads();                      // drains vmcnt(0): K-DMA(i) complete too
    if (i+1 < NTT) stage_issue(i+1, cur^1);

    // === S = Q K^T (raw scores) ===
    f4v s[4];
    #pragma unroll
    for (int n=0;n<4;n++) s[n] = (f4v)0.f;
    #pragma unroll
    for (int kk=0;kk<2;kk++){
      #pragma unroll
      for (int n=0;n<4;n++){
        s8v bf = *(const s8v*)&lsK[cur][(16*n+fr)*64 + (((kk*4+fq) ^ (fr&7))<<3)];
        s[n] = __builtin_amdgcn_mfma_f32_16x16x32_bf16(aq[kk], bf, s[n], 0,0,0);
      }
    }
    // masking: wave-uniform fast path
    const bool isg = (i == 0);
    const int dlt = k0 - q0 - w*16;
    const bool maskAll = __all(lsM[cur][lane] > 0.f);
    const bool fullOK = maskAll && (isg || (dlt >= -241 && dlt <= 193));
    if (!fullOK){
      #pragma unroll
      for (int n=0;n<4;n++){
        const int kcol = 16*n + fr;
        const float mk = lsM[cur][kcol];
        #pragma unroll
        for (int r=0;r<4;r++){
          const int dd = k0 + kcol - (q0 + w*16 + fq*4 + r);
          const bool valid = (mk > 0.f) && (isg || (dd >= -WIN && dd <= WIN));
          s[n][r] = valid ? s[n][r] : NEGS;
        }
      }
    }
    // single-m online softmax, defer-max
    float rm = fmaxf(fmaxf(fmaxf(s[0][0],s[0][1]),fmaxf(s[0][2],s[0][3])),
                     fmaxf(fmaxf(s[1][0],s[1][1]),fmaxf(s[1][2],s[1][3])));
    rm = fmaxf(rm, fmaxf(fmaxf(fmaxf(s[2][0],s[2][1]),fmaxf(s[2][2],s[2][3])),
                         fmaxf(fmaxf(s[3][0],s[3][1]),fmaxf(s[3][2],s[3][3]))));
    rm = fmaxf(rm, __shfl_xor(rm, 1, 64));
    rm = fmaxf(rm, __shfl_xor(rm, 2, 64));
    rm = fmaxf(rm, __shfl_xor(rm, 4, 64));
    rm = fmaxf(rm, __shfl_xor(rm, 8, 64));
    if (__any(rm > m + DEFER)){
      const float mn = fmaxf(m, rm);
      const float sf = exp2f((m - mn)*FOLD);
      m = mn;
      #pragma unroll
      for (int n=0;n<5;n++)
        #pragma unroll
        for (int r=0;r<4;r++) out[n][r] *= sf;
    }
    const float mF = m * FOLD;
    // P = exp2(s*FOLD - mF), store bf16 via cvt_pk
    u16* lsPw = lsP[w];
    #pragma unroll
    for (int r=0;r<4;r++){
      const float p0 = exp2f(fmaf(s[0][r], FOLD, -mF));
      const float p1 = exp2f(fmaf(s[1][r], FOLD, -mF));
      const float p2 = exp2f(fmaf(s[2][r], FOLD, -mF));
      const float p3 = exp2f(fmaf(s[3][r], FOLD, -mF));
      u32 a, c;
      asm("v_cvt_pk_bf16_f32 %0, %1, %2" : "=v"(a) : "v"(p0), "v"(p1));
      asm("v_cvt_pk_bf16_f32 %0, %1, %2" : "=v"(c) : "v"(p2), "v"(p3));
      const int row = (fq*4+r)*72;
      lsPw[row + fr]      = (u16)a;
      lsPw[row + 16 + fr] = (u16)(a >> 16);
      lsPw[row + 32 + fr] = (u16)c;
      lsPw[row + 48 + fr] = (u16)(c >> 16);
    }
    // PV (+ l in out[4] via ones row)
    s8v ap[2];
    ap[0] = *(const s8v*)&lsPw[fr*72 + fq*8];
    ap[1] = *(const s8v*)&lsPw[fr*72 + 32 + fq*8];
    #pragma unroll
    for (int kk=0;kk<2;kk++){
      #pragma unroll
      for (int n=0;n<5;n++){
        s8v bv = *(const s8v*)&lsVT[cur][(16*n+fr)*72 + kk*32 + fq*8];
        out[n] = __builtin_amdgcn_mfma_f32_16x16x32_bf16(ap[kk], bv, out[n], 0,0,0);
      }
    }
    cur ^= 1;
  }
  // l lives in out[4][r] at fr==0 of each fq group
  float linv[4];
  #pragma unroll
  for (int r=0;r<4;r++) linv[r] = 1.f / __shfl(out[4][r], lane & 48, 64);
  u16* cb = ctx + (((long)(b*SL) + q0 + w*16 + fq*4))*DM + h*HD + fr;
  #pragma unroll
  for (int n=0;n<4;n++)
    #pragma unroll
    for (int r=0;r<4;r++)
      cb[(long)r*DM + 16*n] = f2b(out[n][r]*linv[r]);
}

// ---------------------------------------------------------------- global rows, MFMA flash partials
// Grid (KCH, H, B): q-rows 0..63 vs a 128-key chunk (2 tiles), same softmax-lite.
__global__ __launch_bounds__(256, 3)
void attn_global_part(const u16* __restrict__ qkv, const float* __restrict__ mask,
                      float* __restrict__ pout, float* __restrict__ pml)
{
  const int ck = blockIdx.x;
  const int h = blockIdx.y, b = blockIdx.z;
  const int bh = b*NH + h;
  const int t = threadIdx.x;
  const int w = t >> 6, lane = t & 63;
  const int fq = lane >> 4, fr = lane & 15;

  __shared__ u16 lsK[2][64*64];
  __shared__ u16 lsVT[2][80*72];
  __shared__ u16 lsP[4][16*72];
  __shared__ float lsM[2][64];

  for (int e = t; e < 16*72; e += 256){
    const u16 v = (e < 72) ? (u16)0x3F80 : (u16)0;
    lsVT[0][64*72 + e] = v;
    lsVT[1][64*72 + e] = v;
  }

  const long bq = (long)b*SL*QN;
  const u16* qrow = qkv + (bq + (long)(w*16 + fr)*QN) + h*HD;   // q rows 0..63
  s8v aq[2];
  aq[0] = *(const s8v*)(qrow + fq*8);
  aq[1] = *(const s8v*)(qrow + 32 + fq*8);

  const u16* kq = qkv + bq + DM + h*HD;
  const u16* vq = qkv + bq + 2*DM + h*HD;
  const float* mrow = mask + b*SL;

  f4v out[5];
  #pragma unroll
  for (int n=0;n<5;n++) out[n] = (f4v)0.f;
  float m = -3.0e38f;

  us8 vv0, vv1;
  auto stage_issue = [&](int i, int buf){
    const int k0 = ck*128 + i*64;
    if (t < 64) lsM[buf][t] = mrow[k0 + t];
    #pragma unroll
    for (int j=0;j<2;j++){
      const int r = (w*2+j)*8 + (lane>>3);
      const int d = ((lane&7) ^ (lane>>3))*8;
      __builtin_amdgcn_global_load_lds(
        (const __attribute__((address_space(1))) void*)(kq + (long)(k0+r)*QN + d),
        (__attribute__((address_space(3))) void*)(&lsK[buf][(w*2+j)*512]), 16, 0, 0);
    }
    vv0 = *(const us8*)(vq + (long)(k0+lane)*QN + w*8);
    vv1 = *(const us8*)(vq + (long)(k0+lane)*QN + w*8 + 32);
  };

  stage_issue(0, 0);
  int cur = 0;
  for (int i = 0; i < 2; i++){
    const int d0 = w*8;
    #pragma unroll
    for (int jj=0;jj<8;jj++) lsVT[cur][(d0+jj)*72 + lane] = (u16)vv0[jj];
    #pragma unroll
    for (int jj=0;jj<8;jj++) lsVT[cur][(d0+32+jj)*72 + lane] = (u16)vv1[jj];
    __syncthreads();
    if (i+1 < 2) stage_issue(i+1, cur^1);

    f4v s[4];
    #pragma unroll
    for (int n=0;n<4;n++) s[n] = (f4v)0.f;
    #pragma unroll
    for (int kk=0;kk<2;kk++){
      #pragma unroll
      for (int n=0;n<4;n++){
        s8v bf = *(const s8v*)&lsK[cur][(16*n+fr)*64 + (((kk*4+fq) ^ (fr&7))<<3)];
        s[n] = __builtin_amdgcn_mfma_f32_16x16x32_bf16(aq[kk], bf, s[n], 0,0,0);
      }
    }
    const bool fullOK = __all(lsM[cur][lane] > 0.f);
    if (!fullOK){
      #pragma unroll
      for (int n=0;n<4;n++){
        const float mk = lsM[cur][16*n + fr];
        #pragma unroll
        for (int r=0;r<4;r++)
          s[n][r] = (mk > 0.f) ? s[n][r] : NEGS;
      }
    }
    float rm = fmaxf(fmaxf(fmaxf(s[0][0],s[0][1]),fmaxf(s[0][2],s[0][3])),
                     fmaxf(fmaxf(s[1][0],s[1][1]),fmaxf(s[1][2],s[1][3])));
    rm = fmaxf(rm, fmaxf(fmaxf(fmaxf(s[2][0],s[2][1]),fmaxf(s[2][2],s[2][3])),
                         fmaxf(fmaxf(s[3][0],s[3][1]),fmaxf(s[3][2],s[3][3]))));
    rm = fmaxf(rm, __shfl_xor(rm, 1, 64));
    rm = fmaxf(rm, __shfl_xor(rm, 2, 64));
    rm = fmaxf(rm, __shfl_xor(rm, 4, 64));
    rm = fmaxf(rm, __shfl_xor(rm, 8, 64));
    if (__any(rm > m + DEFER)){
      const float mn = fmaxf(m, rm);
      const float sf = exp2f((m - mn)*FOLD);
      m = mn;
      #pragma unroll
      for (int n=0;n<5;n++)
        #pragma unroll
        for (int r=0;r<4;r++) out[n][r] *= sf;
    }
    const float mF = m * FOLD;
    u16* lsPw = lsP[w];
    #pragma unroll
    for (int r=0;r<4;r++){
      const float p0 = exp2f(fmaf(s[0][r], FOLD, -mF));
      const float p1 = exp2f(fmaf(s[1][r], FOLD, -mF));
      const float p2 = exp2f(fmaf(s[2][r], FOLD, -mF));
      const float p3 = exp2f(fmaf(s[3][r], FOLD, -mF));
      u32 a, c;
      asm("v_cvt_pk_bf16_f32 %0, %1, %2" : "=v"(a) : "v"(p0), "v"(p1));
      asm("v_cvt_pk_bf16_f32 %0, %1, %2" : "=v"(c) : "v"(p2), "v"(p3));
      const int row = (fq*4+r)*72;
      lsPw[row + fr]      = (u16)a;
      lsPw[row + 16 + fr] = (u16)(a >> 16);
      lsPw[row + 32 + fr] = (u16)c;
      lsPw[row + 48 + fr] = (u16)(c >> 16);
    }
    s8v ap[2];
    ap[0] = *(const s8v*)&lsPw[fr*72 + fq*8];
    ap[1] = *(const s8v*)&lsPw[fr*72 + 32 + fq*8];
    #pragma unroll
    for (int kk=0;kk<2;kk++){
      #pragma unroll
      for (int n=0;n<5;n++){
        s8v bv = *(const s8v*)&lsVT[cur][(16*n+fr)*72 + kk*32 + fq*8];
        out[n] = __builtin_amdgcn_mfma_f32_16x16x32_bf16(ap[kk], bv, out[n], 0,0,0);
      }
    }
    cur ^= 1;
  }
  float* pob = pout + ((long)(ck*BC*NH + bh))*64*64;
  #pragma unroll
  for (int n=0;n<4;n++)
    #pragma unroll
    for (int r=0;r<4;r++)
      pob[(w*16 + fq*4 + r)*64 + 16*n + fr] = out[n][r];
  if (fr == 0){
    float* pmb = pml + ((long)(ck*BC*NH + bh))*128;
    #pragma unroll
    for (int r=0;r<4;r++){
      pmb[(w*16 + fq*4 + r)*2 + 0] = m * FOLD;      // log2-domain max (combine exps this)
      pmb[(w*16 + fq*4 + r)*2 + 1] = out[4][r];     // l (MFMA ones-column)
    }
  }
}

__global__ __launch_bounds__(256, 2)
void attn_global_combine(const float* __restrict__ pout, const float* __restrict__ pml,
                         u16* __restrict__ ctx)
{
  const int bh = blockIdx.x;
  const int b = bh / NH, h = bh % NH;
  const int t = threadIdx.x;
  __shared__ float wgt[KCH][64];
  __shared__ float rl[64];
  if (t < 64){
    float mc[KCH], lc[KCH];
    #pragma unroll
    for (int c = 0; c < KCH; c++){
      const float* pmb = pml + ((long)(c*BC*NH + bh))*128 + t*2;
      mc[c] = pmb[0]; lc[c] = pmb[1];
    }
    float M = mc[0];
    #pragma unroll
    for (int c = 1; c < KCH; c++) M = fmaxf(M, mc[c]);
    float L = 0.f;
    #pragma unroll
    for (int c = 0; c < KCH; c++){
      const float wv = exp2f(mc[c] - M);
      wgt[c][t] = wv;
      L += lc[c]*wv;
    }
    rl[t] = 1.f/L;
  }
  __syncthreads();
  const int row = t >> 2, dseg = t & 3;
  float acc[16];
  #pragma unroll
  for (int i=0;i<16;i++) acc[i] = 0.f;
  for (int c = 0; c < KCH; c++){
    const float wv = wgt[c][row];
    const float4* pb = (const float4*)(pout + ((long)(c*BC*NH + bh)*64 + row)*64 + dseg*16);
    #pragma unroll
    for (int i = 0; i < 4; i++){
      float4 v = pb[i];
      acc[i*4+0] += v.x*wv; acc[i*4+1] += v.y*wv;
      acc[i*4+2] += v.z*wv; acc[i*4+3] += v.w*wv;
    }
  }
  u16* cr = ctx + ((long)(b*SL + row))*DM + h*HD + dseg*16;
  const float r = rl[row];
  #pragma unroll
  for (int i = 0; i < 16; i += 2){
    u32 pk = (u32)f2b(acc[i]*r) | ((u32)f2b(acc[i+1]*r) << 16);
    *(u32*)(cr + i) = pk;
  }
}

// ---------------------------------------------------------------- LayerNorm + ans/span heads (bf16 h input)
__global__ __launch_bounds__(384, 2)
void ln_heads(const u16* __restrict__ hb, const float* __restrict__ gamma, const float* __restrict__ beta,
              const float* __restrict__ Wa, const float* __restrict__ ba,
              const float* __restrict__ Wsp, const float* __restrict__ bsp,
              float* __restrict__ hn, float* __restrict__ ans, float* __restrict__ span)
{
  const int r = blockIdx.x;
  const int t = threadIdx.x, lane = t & 63, w = t >> 6;   // w in 0..5
  __shared__ float red[12];
  __shared__ float dred[6][5];
  const u32 pk = ((const u32*)(hb + (long)r*DM))[t];
  const float v0 = b2f((u16)(pk & 0xffff));
  const float v1 = b2f((u16)(pk >> 16));
  float sum = wredsum(v0 + v1);
  float sq  = wredsum(v0*v0 + v1*v1);
  if (lane == 0){ red[w] = sum; red[6+w] = sq; }
  __syncthreads();
  float mu = 0.f, msq = 0.f;
  #pragma unroll
  for (int i=0;i<6;i++){ mu += red[i]; msq += red[6+i]; }
  mu *= (1.f/768.f); msq *= (1.f/768.f);
  const float rstd = rsqrtf(msq - mu*mu + 1e-5f);
  const int i0 = 2*t, i1 = 2*t+1;
  const float y0 = (v0 - mu)*rstd*gamma[i0] + beta[i0];
  const float y1 = (v1 - mu)*rstd*gamma[i1] + beta[i1];
  ((float2*)(hn + (long)r*DM))[t] = make_float2(y0, y1);
  float pa0 = y0*Wa[i0*3+0] + y1*Wa[i1*3+0];
  float pa1 = y0*Wa[i0*3+1] + y1*Wa[i1*3+1];
  float pa2 = y0*Wa[i0*3+2] + y1*Wa[i1*3+2];
  float ps0 = y0*Wsp[i0*2+0] + y1*Wsp[i1*2+0];
  float ps1 = y0*Wsp[i0*2+1] + y1*Wsp[i1*2+1];
  pa0 = wredsum(pa0); pa1 = wredsum(pa1); pa2 = wredsum(pa2);
  ps0 = wredsum(ps0); ps1 = wredsum(ps1);
  if (lane == 0){ dred[w][0]=pa0; dred[w][1]=pa1; dred[w][2]=pa2; dred[w][3]=ps0; dred[w][4]=ps1; }
  __syncthreads();
  if (t == 0){
    float A0=0,A1=0,A2=0,S0=0,S1=0;
    #pragma unroll
    for (int i=0;i<6;i++){ A0+=dred[i][0]; A1+=dred[i][1]; A2+=dred[i][2]; S0+=dred[i][3]; S1+=dred[i][4]; }
    ans[(long)r*3+0]  = sigf(A0 + ba[0]);
    ans[(long)r*3+1]  = sigf(A1 + ba[1]);
    ans[(long)r*3+2]  = sigf(A2 + ba[2]);
    span[(long)r*2+0] = sigf(S0 + bsp[0]);
    span[(long)r*2+1] = sigf(S1 + bsp[1]);
  }
}

// ---------------------------------------------------------------- launch
extern "C" void kernel_launch(void* const* d_in, const int* in_sizes, int n_in,
                              void* d_out, int out_size, void* d_ws, size_t ws_size,
                              hipStream_t stream)
{
  const int*   input_ids = (const int*)  d_in[0];
  const float* attn_mask = (const float*)d_in[1];
  const int*   html_idx  = (const int*)  d_in[2];
  const float* embed     = (const float*)d_in[3];
  const float* Wq = (const float*)d_in[4];  const float* bq = (const float*)d_in[5];
  const float* Wk = (const float*)d_in[6];  const float* bk = (const float*)d_in[7];
  const float* Wv = (const float*)d_in[8];  const float* bv = (const float*)d_in[9];
  const float* Wo = (const float*)d_in[10]; const float* bo = (const float*)d_in[11];
  const float* gamma = (const float*)d_in[12]; const float* beta = (const float*)d_in[13];
  const float* Wp = (const float*)d_in[14]; const float* bp = (const float*)d_in[15];
  const float* Wa = (const float*)d_in[16]; const float* ba = (const float*)d_in[17];
  const float* Wsp = (const float*)d_in[18]; const float* bsp = (const float*)d_in[19];

  char* ws = (char*)d_ws;
  size_t off = 0;
  auto take = [&](size_t bytes)->char*{
    char* p = ws + off; off += (bytes + 255) & ~(size_t)255; return p;
  };
  u16*   x_b    = (u16*)  take((size_t)8192*768*2);
  u16*   wt_qkv = (u16*)  take((size_t)2304*768*2);
  u16*   wt_o   = (u16*)  take((size_t)768*768*2);
  u16*   wt_p   = (u16*)  take((size_t)768*768*2);
  float* b_qkv  = (float*)take(2304*4);
  u16*   qkv_b  = (u16*)  take((size_t)8192*2304*2);
  u16*   ctx_b  = (u16*)  take((size_t)8192*768*2);
  u16*   h_b    = (u16*)  take((size_t)8192*768*2);
  u16*   hr_b   = (u16*)  take((size_t)512*768*2);
  u16*   t_b    = (u16*)  take((size_t)512*768*2);
  float* pout   = (float*)take((size_t)KCH*BC*NH*64*64*4);
  float* pml    = (float*)take((size_t)KCH*BC*NH*128*4);

  float* out_hn   = (float*)d_out;
  float* out_ans  = out_hn  + (size_t)8192*768;
  float* out_span = out_ans + (size_t)8192*3;
  float* out_cond = out_span + (size_t)8192*2;

  pack_embed<<<6864, 256, 0, stream>>>(Wq, Wk, Wv, Wo, Wp, bq, bk, bv,
                                       wt_qkv, wt_o, wt_p, b_qkv,
                                       input_ids, embed, x_b);

  gemm_bt<0,true><<<dim3(18,64,1), 256, 0, stream>>>(x_b, wt_qkv, b_qkv, nullptr,
                                                nullptr, qkv_b, 8192, 2304, 768, 0,0,0);
  attn_band_mfma<<<dim3(64,12,2), 256, 0, stream>>>(qkv_b, attn_mask, ctx_b);
  attn_global_part<<<dim3(KCH,12,2), 256, 0, stream>>>(qkv_b, attn_mask, pout, pml);
  attn_global_combine<<<BC*NH, 256, 0, stream>>>(pout, pml, ctx_b);
  gemm_bt<1,true><<<dim3(6,64,1), 256, 0, stream>>>(ctx_b, wt_o, bo, x_b,
                                               nullptr, h_b, 8192, 768, 768, 0,0,0);
  ln_heads<<<8192, 384, 0, stream>>>(h_b, gamma, beta, Wa, ba, Wsp, bsp,
                                     out_hn, out_ans, out_span);
  gather_hr<<<1536, 256, 0, stream>>>(html_idx, out_hn, hr_b);
  gemm_bt<2,false><<<dim3(6,4,1), 256, 0, stream>>>(hr_b, wt_p, bp, nullptr,
                                              nullptr, t_b, 512, 768, 768, 0,0,0);
  gemm_bt<3,false><<<dim3(2,2,2), 256, 0, stream>>>(t_b, hr_b, nullptr, nullptr,
                                              out_cond, nullptr, 256, 256, 768,
                                              (long)256*768, (long)256*768, (long)256*256);
}

// Round 8
// 221.860 us; speedup vs baseline: 1.1755x; 1.0329x over previous
//
#include <hip/hip_runtime.h>

typedef unsigned short u16;
typedef unsigned int   u32;
typedef __attribute__((ext_vector_type(8))) short s8v;           // MFMA bf16 frag (8 bf16)
typedef __attribute__((ext_vector_type(8))) unsigned short us8;  // raw bf16x8 load
typedef __attribute__((ext_vector_type(4))) float f4v;           // MFMA acc frag

constexpr int BC  = 2;
constexpr int SL  = 4096;
constexpr int NH  = 12;
constexpr int HD  = 64;
constexpr int DM  = 768;
constexpr int WIN = 256;
constexpr int GLB = 64;
constexpr int QN  = 2304;   // q|k|v packed columns
constexpr int KCH = 32;     // global-attn key chunks (128 keys each)
constexpr float FOLD = 0.125f * 1.44269504088896f; // scale(1/sqrt(64)) * log2(e)
constexpr float NEGS = -1.0e9f;
constexpr float DEFER = 44.36f;                    // 8 / FOLD (defer-max threshold, raw units)

__device__ __forceinline__ float b2f(u16 b){ return __uint_as_float(((u32)b) << 16); }
__device__ __forceinline__ u16 f2b(float f){
  u32 u = __float_as_uint(f);
  return (u16)((u + 0x7fffu + ((u >> 16) & 1u)) >> 16);  // RNE
}
__device__ __forceinline__ float wredsum(float v){
  #pragma unroll
  for (int o = 32; o > 0; o >>= 1) v += __shfl_xor(v, o, 64);
  return v;
}
__device__ __forceinline__ float sigf(float x){ return 1.f / (1.f + __expf(-x)); }

// ---------------------------------------------------------------- fused weight pack + embed gather
__global__ void pack_embed(const float* __restrict__ Wq, const float* __restrict__ Wk,
                           const float* __restrict__ Wv, const float* __restrict__ Wo,
                           const float* __restrict__ Wp,
                           const float* __restrict__ bq, const float* __restrict__ bk,
                           const float* __restrict__ bv,
                           u16* __restrict__ wt_qkv, u16* __restrict__ wt_o,
                           u16* __restrict__ wt_p, float* __restrict__ b_qkv,
                           const int* __restrict__ ids, const float* __restrict__ emb,
                           u16* __restrict__ xb)
{
  __shared__ float tile[64][65];
  const int bid = blockIdx.x;
  const int t = threadIdx.x;
  if (bid < 720){
    const int mi = bid / 144, rest = bid % 144;
    const int kt = rest / 12, ntc = rest % 12;
    const float* src = (mi==0)?Wq:(mi==1)?Wk:(mi==2)?Wv:(mi==3)?Wo:Wp;
    u16* dst = (mi<3) ? (wt_qkv + (size_t)mi*768*768) : ((mi==3) ? wt_o : wt_p);
    const int k0 = kt*64, n0 = ntc*64;
    #pragma unroll
    for (int i=0;i<4;i++){
      const int r = (t>>4) + i*16;
      float4 v = ((const float4*)(src + (long)(k0+r)*768 + n0))[t&15];
      tile[r][(t&15)*4+0] = v.x; tile[r][(t&15)*4+1] = v.y;
      tile[r][(t&15)*4+2] = v.z; tile[r][(t&15)*4+3] = v.w;
    }
    __syncthreads();
    const int n = t & 63, kc = (t>>6)*16;
    u32* d32 = (u32*)(dst + (long)(n0+n)*768 + k0 + kc);
    #pragma unroll
    for (int i=0;i<8;i++){
      d32[i] = (u32)f2b(tile[kc+2*i][n]) | ((u32)f2b(tile[kc+2*i+1][n]) << 16);
    }
    if (bid < 9){
      const int i = bid*256 + t;
      if (i < 2304) b_qkv[i] = (i < 768) ? bq[i] : (i < 1536) ? bk[i-768] : bv[i-1536];
    }
  } else {
    int e4 = (bid-720)*256 + t;                  // 8192 rows * 192 float4
    int row = e4 / 192, d4 = e4 - row*192;
    int id = ids[row];
    float4 v = ((const float4*)(emb + (long)id*768))[d4];
    u32 p0 = (u32)f2b(v.x) | ((u32)f2b(v.y) << 16);
    u32 p1 = (u32)f2b(v.z) | ((u32)f2b(v.w) << 16);
    ((u32*)(xb + (long)row*768))[d4*2]   = p0;
    ((u32*)(xb + (long)row*768))[d4*2+1] = p1;
  }
}

__global__ void gather_hr(const int* __restrict__ hidx, const float* __restrict__ hn,
                          u16* __restrict__ hrb){
  int e = blockIdx.x*256 + threadIdx.x;          // 512 rows * 768
  if (e >= 512*768) return;
  int r = e / 768, d = e - r*768;
  int b = r >> 8;
  int idx = hidx[r];
  hrb[e] = f2b(hn[((long)(b*SL + idx))*768 + d]);
}

// ---------------------------------------------------------------- bf16 MFMA GEMM
template<int MODE, bool SWZ>
__global__ __launch_bounds__(256, 2)
void gemm_bt(const u16* __restrict__ A, const u16* __restrict__ Bt,
             const float* __restrict__ bias, const u16* __restrict__ resB,
             float* __restrict__ outF, u16* __restrict__ outB,
             int M, int N, int K, long sA, long sB, long sO)
{
  const int bz = blockIdx.z;
  A  += (long)bz * sA;
  Bt += (long)bz * sB;
  int vid = blockIdx.x + gridDim.x*blockIdx.y;
  if constexpr (SWZ){
    const int chunk = (gridDim.x*gridDim.y) >> 3;
    vid = (vid & 7)*chunk + (vid >> 3);
  }
  const int n0 = (vid % gridDim.x) * 128;
  const int m0 = (vid / gridDim.x) * 128;
  __shared__ u16 lsA[128*64];
  __shared__ u16 lsB[128*64];
  const int t = threadIdx.x;
  const int w = t >> 6, lane = t & 63;
  const int wr = w >> 1, wc = w & 1;
  const int fr = lane & 15, fq = lane >> 4;

  f4v acc[4][4];
  #pragma unroll
  for (int i=0;i<4;i++)
    #pragma unroll
    for (int j=0;j<4;j++) acc[i][j] = (f4v)0.f;

  for (int k0 = 0; k0 < K; k0 += 64){
    #pragma unroll
    for (int i=0;i<4;i++){
      int e = (w*4+i)*512 + lane*8;
      int row = e >> 6, col = e & 63;
      __builtin_amdgcn_global_load_lds(
        (const __attribute__((address_space(1))) void*)(A + (long)(m0+row)*K + (k0+col)),
        (__attribute__((address_space(3))) void*)(&lsA[(w*4+i)*512]), 16, 0, 0);
      __builtin_amdgcn_global_load_lds(
        (const __attribute__((address_space(1))) void*)(Bt + (long)(n0+row)*K + (k0+col)),
        (__attribute__((address_space(3))) void*)(&lsB[(w*4+i)*512]), 16, 0, 0);
    }
    __syncthreads();
    #pragma unroll
    for (int kk = 0; kk < 2; kk++){
      s8v af[4], bfv[4];
      #pragma unroll
      for (int mi=0;mi<4;mi++)
        af[mi] = *(const s8v*)&lsA[(wr*64 + mi*16 + fr)*64 + kk*32 + fq*8];
      #pragma unroll
      for (int ni=0;ni<4;ni++)
        bfv[ni] = *(const s8v*)&lsB[(wc*64 + ni*16 + fr)*64 + kk*32 + fq*8];
      #pragma unroll
      for (int mi=0;mi<4;mi++)
        #pragma unroll
        for (int ni=0;ni<4;ni++)
          acc[mi][ni] = __builtin_amdgcn_mfma_f32_16x16x32_bf16(af[mi], bfv[ni], acc[mi][ni], 0, 0, 0);
    }
    __syncthreads();
  }
  #pragma unroll
  for (int mi=0;mi<4;mi++){
    #pragma unroll
    for (int ni=0;ni<4;ni++){
      #pragma unroll
      for (int r=0;r<4;r++){
        int row = m0 + wr*64 + mi*16 + fq*4 + r;
        int col = n0 + wc*64 + ni*16 + fr;
        float v = acc[mi][ni][r];
        if constexpr (MODE == 0){
          v += bias[col];
          outB[(long)row*N + col] = f2b(v);
        } else if constexpr (MODE == 1){
          v += bias[col] + b2f(resB[(long)row*N + col]);
          outB[(long)row*N + col] = f2b(v);
        } else if constexpr (MODE == 2){
          v = fmaxf(v + bias[col], 0.f);
          outB[(long)row*N + col] = f2b(v);
        } else {
          (outF + bz*sO)[(long)row*N + col] = sigf(v);
        }
      }
    }
  }
}

// ---------------------------------------------------------------- banded attention, MFMA flash
// QBLK=64, 4 waves x 16 q rows. LDS trimmed to 36.4 KB -> 4 blocks/CU:
//   K single-buffered (restaged after a post-QK barrier), V/mask double-buffered,
//   l via constant reg-ones MFMA B-fragment (no LDS ones rows, no shuffles).
// Hazards (2 barriers/tile): V-write(i) -> bar_a [drains K-DMA(i) vmcnt] -> QK(i)
// reads lsK -> bar_b [all QK reads done] -> issue K-DMA(i+1)/V-loads(i+1)/mask(i+1)
// -> softmax/PV(i). lsM/lsVT buffers written here were last read 2 barriers ago.
__global__ __launch_bounds__(256, 4)
void attn_band_mfma(const u16* __restrict__ qkv, const float* __restrict__ mask, u16* __restrict__ ctx)
{
  const int q0 = blockIdx.x * 64;
  const int h = blockIdx.y, b = blockIdx.z;
  const int t = threadIdx.x;
  const int w = t >> 6, lane = t & 63;
  const int fq = lane >> 4, fr = lane & 15;

  __shared__ u16 lsK[64*64];       // single buffer; row r chunk c8 holds K[r][(c8^(r&7))*8..)
  __shared__ u16 lsVT[2][64*72];   // V^T[d][k], row stride 72
  __shared__ u16 lsP[4][16*72];    // per-wave P
  __shared__ float lsM[2][64];

  const long bq = (long)b*SL*QN;
  const u16* qrow = qkv + (bq + (long)(q0 + w*16 + fr)*QN) + h*HD;
  s8v aq[2];
  aq[0] = *(const s8v*)(qrow + fq*8);
  aq[1] = *(const s8v*)(qrow + 32 + fq*8);

  // constant B-fragment: column 0 = ones -> outl col0 = sum_k P
  s8v ones_bf;
  {
    const short o = (fr == 0) ? (short)0x3F80 : (short)0;
    #pragma unroll
    for (int j=0;j<8;j++) ones_bf[j] = o;
  }

  const u16* kq = qkv + bq + DM + h*HD;
  const u16* vq = qkv + bq + 2*DM + h*HD;
  const float* mrow = mask + b*SL;

  const int ti_lo = (q0 < 320) ? ((320 - q0) >> 6) : 0;
  const int ti_hi_raw = (4352 - q0) >> 6;
  const int ti_hi = ti_hi_raw < 9 ? ti_hi_raw : 9;
  const int NTT = 1 + (ti_hi - ti_lo);
  const int kb0 = q0 - 256 + ti_lo*64;

  f4v out[4];
  f4v outl = (f4v)0.f;
  #pragma unroll
  for (int n=0;n<4;n++) out[n] = (f4v)0.f;
  float m = -3.0e38f;

  us8 vv0, vv1;
  auto stage_issue = [&](int i, int vbuf){
    const int k0 = (i == 0) ? 0 : kb0 + (i-1)*64;
    if (t < 64) lsM[vbuf][t] = mrow[k0 + t];
    #pragma unroll
    for (int j=0;j<2;j++){
      const int r = (w*2+j)*8 + (lane>>3);
      const int d = ((lane&7) ^ (lane>>3))*8;          // pre-swizzled source col
      __builtin_amdgcn_global_load_lds(
        (const __attribute__((address_space(1))) void*)(kq + (long)(k0+r)*QN + d),
        (__attribute__((address_space(3))) void*)(&lsK[(w*2+j)*512]), 16, 0, 0);
    }
    vv0 = *(const us8*)(vq + (long)(k0+lane)*QN + w*8);
    vv1 = *(const us8*)(vq + (long)(k0+lane)*QN + w*8 + 32);
  };

  stage_issue(0, 0);
  int cur = 0;
  for (int i = 0; i < NTT; i++){
    const int k0 = (i == 0) ? 0 : kb0 + (i-1)*64;
    const int d0 = w*8;
    #pragma unroll
    for (int jj=0;jj<8;jj++) lsVT[cur][(d0+jj)*72 + lane] = (u16)vv0[jj];
    #pragma unroll
    for (int jj=0;jj<8;jj++) lsVT[cur][(d0+32+jj)*72 + lane] = (u16)vv1[jj];
    __syncthreads();                      // bar_a: K(i) DMA + V(i)/mask(i) visible

    // === S = Q K^T (raw scores) from lsK ===
    f4v s[4];
    #pragma unroll
    for (int n=0;n<4;n++) s[n] = (f4v)0.f;
    #pragma unroll
    for (int kk=0;kk<2;kk++){
      #pragma unroll
      for (int n=0;n<4;n++){
        s8v bf = *(const s8v*)&lsK[(16*n+fr)*64 + (((kk*4+fq) ^ (fr&7))<<3)];
        s[n] = __builtin_amdgcn_mfma_f32_16x16x32_bf16(aq[kk], bf, s[n], 0,0,0);
      }
    }
    __syncthreads();                      // bar_b: all waves' lsK reads done
    if (i+1 < NTT) stage_issue(i+1, cur^1);   // K-DMA overwrites lsK; V/mask -> buf^1

    // masking: wave-uniform fast path
    const bool isg = (i == 0);
    const int dlt = k0 - q0 - w*16;
    const bool maskAll = __all(lsM[cur][lane] > 0.f);
    const bool fullOK = maskAll && (isg || (dlt >= -241 && dlt <= 193));
    if (!fullOK){
      #pragma unroll
      for (int n=0;n<4;n++){
        const int kcol = 16*n + fr;
        const float mk = lsM[cur][kcol];
        #pragma unroll
        for (int r=0;r<4;r++){
          const int dd = k0 + kcol - (q0 + w*16 + fq*4 + r);
          const bool valid = (mk > 0.f) && (isg || (dd >= -WIN && dd <= WIN));
          s[n][r] = valid ? s[n][r] : NEGS;
        }
      }
    }
    // single-m online softmax, lane-local defer check (shuffle-reduce only on demand)
    float rmloc = fmaxf(fmaxf(fmaxf(s[0][0],s[0][1]),fmaxf(s[0][2],s[0][3])),
                        fmaxf(fmaxf(s[1][0],s[1][1]),fmaxf(s[1][2],s[1][3])));
    rmloc = fmaxf(rmloc, fmaxf(fmaxf(fmaxf(s[2][0],s[2][1]),fmaxf(s[2][2],s[2][3])),
                               fmaxf(fmaxf(s[3][0],s[3][1]),fmaxf(s[3][2],s[3][3]))));
    if (__any(rmloc > m + DEFER)){
      float rm = rmloc;
      rm = fmaxf(rm, __shfl_xor(rm, 1, 64));
      rm = fmaxf(rm, __shfl_xor(rm, 2, 64));
      rm = fmaxf(rm, __shfl_xor(rm, 4, 64));
      rm = fmaxf(rm, __shfl_xor(rm, 8, 64));
      const float mn = fmaxf(m, rm);
      const float sf = exp2f((m - mn)*FOLD);
      m = mn;
      outl *= sf;
      #pragma unroll
      for (int n=0;n<4;n++)
        #pragma unroll
        for (int r=0;r<4;r++) out[n][r] *= sf;
    }
    const float mF = m * FOLD;
    u16* lsPw = lsP[w];
    #pragma unroll
    for (int r=0;r<4;r++){
      const float p0 = exp2f(fmaf(s[0][r], FOLD, -mF));
      const float p1 = exp2f(fmaf(s[1][r], FOLD, -mF));
      const float p2 = exp2f(fmaf(s[2][r], FOLD, -mF));
      const float p3 = exp2f(fmaf(s[3][r], FOLD, -mF));
      u32 a, c;
      asm("v_cvt_pk_bf16_f32 %0, %1, %2" : "=v"(a) : "v"(p0), "v"(p1));
      asm("v_cvt_pk_bf16_f32 %0, %1, %2" : "=v"(c) : "v"(p2), "v"(p3));
      const int row = (fq*4+r)*72;
      lsPw[row + fr]      = (u16)a;
      lsPw[row + 16 + fr] = (u16)(a >> 16);
      lsPw[row + 32 + fr] = (u16)c;
      lsPw[row + 48 + fr] = (u16)(c >> 16);
    }
    // PV (+ l via reg-ones fragment)
    s8v ap[2];
    ap[0] = *(const s8v*)&lsPw[fr*72 + fq*8];
    ap[1] = *(const s8v*)&lsPw[fr*72 + 32 + fq*8];
    #pragma unroll
    for (int kk=0;kk<2;kk++){
      #pragma unroll
      for (int n=0;n<4;n++){
        s8v bv = *(const s8v*)&lsVT[cur][(16*n+fr)*72 + kk*32 + fq*8];
        out[n] = __builtin_amdgcn_mfma_f32_16x16x32_bf16(ap[kk], bv, out[n], 0,0,0);
      }
      outl = __builtin_amdgcn_mfma_f32_16x16x32_bf16(ap[kk], ones_bf, outl, 0,0,0);
    }
    cur ^= 1;
  }
  float linv[4];
  #pragma unroll
  for (int r=0;r<4;r++) linv[r] = 1.f / __shfl(outl[r], lane & 48, 64);
  u16* cb = ctx + (((long)(b*SL) + q0 + w*16 + fq*4))*DM + h*HD + fr;
  #pragma unroll
  for (int n=0;n<4;n++)
    #pragma unroll
    for (int r=0;r<4;r++)
      cb[(long)r*DM + 16*n] = f2b(out[n][r]*linv[r]);
}

// ---------------------------------------------------------------- global rows, MFMA flash partials
// Same trimmed-LDS 2-barrier structure; q-rows 0..63 vs a 128-key chunk (2 tiles).
__global__ __launch_bounds__(256, 4)
void attn_global_part(const u16* __restrict__ qkv, const float* __restrict__ mask,
                      float* __restrict__ pout, float* __restrict__ pml)
{
  const int ck = blockIdx.x;
  const int h = blockIdx.y, b = blockIdx.z;
  const int bh = b*NH + h;
  const int t = threadIdx.x;
  const int w = t >> 6, lane = t & 63;
  const int fq = lane >> 4, fr = lane & 15;

  __shared__ u16 lsK[64*64];
  __shared__ u16 lsVT[2][64*72];
  __shared__ u16 lsP[4][16*72];
  __shared__ float lsM[2][64];

  const long bq = (long)b*SL*QN;
  const u16* qrow = qkv + (bq + (long)(w*16 + fr)*QN) + h*HD;   // q rows 0..63
  s8v aq[2];
  aq[0] = *(const s8v*)(qrow + fq*8);
  aq[1] = *(const s8v*)(qrow + 32 + fq*8);

  s8v ones_bf;
  {
    const short o = (fr == 0) ? (short)0x3F80 : (short)0;
    #pragma unroll
    for (int j=0;j<8;j++) ones_bf[j] = o;
  }

  const u16* kq = qkv + bq + DM + h*HD;
  const u16* vq = qkv + bq + 2*DM + h*HD;
  const float* mrow = mask + b*SL;

  f4v out[4];
  f4v outl = (f4v)0.f;
  #pragma unroll
  for (int n=0;n<4;n++) out[n] = (f4v)0.f;
  float m = -3.0e38f;

  us8 vv0, vv1;
  auto stage_issue = [&](int i, int vbuf){
    const int k0 = ck*128 + i*64;
    if (t < 64) lsM[vbuf][t] = mrow[k0 + t];
    #pragma unroll
    for (int j=0;j<2;j++){
      const int r = (w*2+j)*8 + (lane>>3);
      const int d = ((lane&7) ^ (lane>>3))*8;
      __builtin_amdgcn_global_load_lds(
        (const __attribute__((address_space(1))) void*)(kq + (long)(k0+r)*QN + d),
        (__attribute__((address_space(3))) void*)(&lsK[(w*2+j)*512]), 16, 0, 0);
    }
    vv0 = *(const us8*)(vq + (long)(k0+lane)*QN + w*8);
    vv1 = *(const us8*)(vq + (long)(k0+lane)*QN + w*8 + 32);
  };

  stage_issue(0, 0);
  int cur = 0;
  for (int i = 0; i < 2; i++){
    const int d0 = w*8;
    #pragma unroll
    for (int jj=0;jj<8;jj++) lsVT[cur][(d0+jj)*72 + lane] = (u16)vv0[jj];
    #pragma unroll
    for (int jj=0;jj<8;jj++) lsVT[cur][(d0+32+jj)*72 + lane] = (u16)vv1[jj];
    __syncthreads();                      // bar_a

    f4v s[4];
    #pragma unroll
    for (int n=0;n<4;n++) s[n] = (f4v)0.f;
    #pragma unroll
    for (int kk=0;kk<2;kk++){
      #pragma unroll
      for (int n=0;n<4;n++){
        s8v bf = *(const s8v*)&lsK[(16*n+fr)*64 + (((kk*4+fq) ^ (fr&7))<<3)];
        s[n] = __builtin_amdgcn_mfma_f32_16x16x32_bf16(aq[kk], bf, s[n], 0,0,0);
      }
    }
    __syncthreads();                      // bar_b
    if (i+1 < 2) stage_issue(i+1, cur^1);

    const bool fullOK = __all(lsM[cur][lane] > 0.f);
    if (!fullOK){
      #pragma unroll
      for (int n=0;n<4;n++){
        const float mk = lsM[cur][16*n + fr];
        #pragma unroll
        for (int r=0;r<4;r++)
          s[n][r] = (mk > 0.f) ? s[n][r] : NEGS;
      }
    }
    float rmloc = fmaxf(fmaxf(fmaxf(s[0][0],s[0][1]),fmaxf(s[0][2],s[0][3])),
                        fmaxf(fmaxf(s[1][0],s[1][1]),fmaxf(s[1][2],s[1][3])));
    rmloc = fmaxf(rmloc, fmaxf(fmaxf(fmaxf(s[2][0],s[2][1]),fmaxf(s[2][2],s[2][3])),
                               fmaxf(fmaxf(s[3][0],s[3][1]),fmaxf(s[3][2],s[3][3]))));
    if (__any(rmloc > m + DEFER)){
      float rm = rmloc;
      rm = fmaxf(rm, __shfl_xor(rm, 1, 64));
      rm = fmaxf(rm, __shfl_xor(rm, 2, 64));
      rm = fmaxf(rm, __shfl_xor(rm, 4, 64));
      rm = fmaxf(rm, __shfl_xor(rm, 8, 64));
      const float mn = fmaxf(m, rm);
      const float sf = exp2f((m - mn)*FOLD);
      m = mn;
      outl *= sf;
      #pragma unroll
      for (int n=0;n<4;n++)
        #pragma unroll
        for (int r=0;r<4;r++) out[n][r] *= sf;
    }
    const float mF = m * FOLD;
    u16* lsPw = lsP[w];
    #pragma unroll
    for (int r=0;r<4;r++){
      const float p0 = exp2f(fmaf(s[0][r], FOLD, -mF));
      const float p1 = exp2f(fmaf(s[1][r], FOLD, -mF));
      const float p2 = exp2f(fmaf(s[2][r], FOLD, -mF));
      const float p3 = exp2f(fmaf(s[3][r], FOLD, -mF));
      u32 a, c;
      asm("v_cvt_pk_bf16_f32 %0, %1, %2" : "=v"(a) : "v"(p0), "v"(p1));
      asm("v_cvt_pk_bf16_f32 %0, %1, %2" : "=v"(c) : "v"(p2), "v"(p3));
      const int row = (fq*4+r)*72;
      lsPw[row + fr]      = (u16)a;
      lsPw[row + 16 + fr] = (u16)(a >> 16);
      lsPw[row + 32 + fr] = (u16)c;
      lsPw[row + 48 + fr] = (u16)(c >> 16);
    }
    s8v ap[2];
    ap[0] = *(const s8v*)&lsPw[fr*72 + fq*8];
    ap[1] = *(const s8v*)&lsPw[fr*72 + 32 + fq*8];
    #pragma unroll
    for (int kk=0;kk<2;kk++){
      #pragma unroll
      for (int n=0;n<4;n++){
        s8v bv = *(const s8v*)&lsVT[cur][(16*n+fr)*72 + kk*32 + fq*8];
        out[n] = __builtin_amdgcn_mfma_f32_16x16x32_bf16(ap[kk], bv, out[n], 0,0,0);
      }
      outl = __builtin_amdgcn_mfma_f32_16x16x32_bf16(ap[kk], ones_bf, outl, 0,0,0);
    }
    cur ^= 1;
  }
  float* pob = pout + ((long)(ck*BC*NH + bh))*64*64;
  #pragma unroll
  for (int n=0;n<4;n++)
    #pragma unroll
    for (int r=0;r<4;r++)
      pob[(w*16 + fq*4 + r)*64 + 16*n + fr] = out[n][r];
  if (fr == 0){
    float* pmb = pml + ((long)(ck*BC*NH + bh))*128;
    #pragma unroll
    for (int r=0;r<4;r++){
      pmb[(w*16 + fq*4 + r)*2 + 0] = m * FOLD;      // log2-domain max
      pmb[(w*16 + fq*4 + r)*2 + 1] = outl[r];       // l (reg-ones MFMA column)
    }
  }
}

__global__ __launch_bounds__(256, 2)
void attn_global_combine(const float* __restrict__ pout, const float* __restrict__ pml,
                         u16* __restrict__ ctx)
{
  const int bh = blockIdx.x;
  const int b = bh / NH, h = bh % NH;
  const int t = threadIdx.x;
  __shared__ float wgt[KCH][64];
  __shared__ float rl[64];
  if (t < 64){
    float mc[KCH], lc[KCH];
    #pragma unroll
    for (int c = 0; c < KCH; c++){
      const float* pmb = pml + ((long)(c*BC*NH + bh))*128 + t*2;
      mc[c] = pmb[0]; lc[c] = pmb[1];
    }
    float M = mc[0];
    #pragma unroll
    for (int c = 1; c < KCH; c++) M = fmaxf(M, mc[c]);
    float L = 0.f;
    #pragma unroll
    for (int c = 0; c < KCH; c++){
      const float wv = exp2f(mc[c] - M);
      wgt[c][t] = wv;
      L += lc[c]*wv;
    }
    rl[t] = 1.f/L;
  }
  __syncthreads();
  const int row = t >> 2, dseg = t & 3;
  float acc[16];
  #pragma unroll
  for (int i=0;i<16;i++) acc[i] = 0.f;
  for (int c = 0; c < KCH; c++){
    const float wv = wgt[c][row];
    const float4* pb = (const float4*)(pout + ((long)(c*BC*NH + bh)*64 + row)*64 + dseg*16);
    #pragma unroll
    for (int i = 0; i < 4; i++){
      float4 v = pb[i];
      acc[i*4+0] += v.x*wv; acc[i*4+1] += v.y*wv;
      acc[i*4+2] += v.z*wv; acc[i*4+3] += v.w*wv;
    }
  }
  u16* cr = ctx + ((long)(b*SL + row))*DM + h*HD + dseg*16;
  const float r = rl[row];
  #pragma unroll
  for (int i = 0; i < 16; i += 2){
    u32 pk = (u32)f2b(acc[i]*r) | ((u32)f2b(acc[i+1]*r) << 16);
    *(u32*)(cr + i) = pk;
  }
}

// ---------------------------------------------------------------- LayerNorm + ans/span heads (bf16 h input)
__global__ __launch_bounds__(384, 2)
void ln_heads(const u16* __restrict__ hb, const float* __restrict__ gamma, const float* __restrict__ beta,
              const float* __restrict__ Wa, const float* __restrict__ ba,
              const float* __restrict__ Wsp, const float* __restrict__ bsp,
              float* __restrict__ hn, float* __restrict__ ans, float* __restrict__ span)
{
  const int r = blockIdx.x;
  const int t = threadIdx.x, lane = t & 63, w = t >> 6;   // w in 0..5
  __shared__ float red[12];
  __shared__ float dred[6][5];
  const u32 pk = ((const u32*)(hb + (long)r*DM))[t];
  const float v0 = b2f((u16)(pk & 0xffff));
  const float v1 = b2f((u16)(pk >> 16));
  float sum = wredsum(v0 + v1);
  float sq  = wredsum(v0*v0 + v1*v1);
  if (lane == 0){ red[w] = sum; red[6+w] = sq; }
  __syncthreads();
  float mu = 0.f, msq = 0.f;
  #pragma unroll
  for (int i=0;i<6;i++){ mu += red[i]; msq += red[6+i]; }
  mu *= (1.f/768.f); msq *= (1.f/768.f);
  const float rstd = rsqrtf(msq - mu*mu + 1e-5f);
  const int i0 = 2*t, i1 = 2*t+1;
  const float y0 = (v0 - mu)*rstd*gamma[i0] + beta[i0];
  const float y1 = (v1 - mu)*rstd*gamma[i1] + beta[i1];
  ((float2*)(hn + (long)r*DM))[t] = make_float2(y0, y1);
  float pa0 = y0*Wa[i0*3+0] + y1*Wa[i1*3+0];
  float pa1 = y0*Wa[i0*3+1] + y1*Wa[i1*3+1];
  float pa2 = y0*Wa[i0*3+2] + y1*Wa[i1*3+2];
  float ps0 = y0*Wsp[i0*2+0] + y1*Wsp[i1*2+0];
  float ps1 = y0*Wsp[i0*2+1] + y1*Wsp[i1*2+1];
  pa0 = wredsum(pa0); pa1 = wredsum(pa1); pa2 = wredsum(pa2);
  ps0 = wredsum(ps0); ps1 = wredsum(ps1);
  if (lane == 0){ dred[w][0]=pa0; dred[w][1]=pa1; dred[w][2]=pa2; dred[w][3]=ps0; dred[w][4]=ps1; }
  __syncthreads();
  if (t == 0){
    float A0=0,A1=0,A2=0,S0=0,S1=0;
    #pragma unroll
    for (int i=0;i<6;i++){ A0+=dred[i][0]; A1+=dred[i][1]; A2+=dred[i][2]; S0+=dred[i][3]; S1+=dred[i][4]; }
    ans[(long)r*3+0]  = sigf(A0 + ba[0]);
    ans[(long)r*3+1]  = sigf(A1 + ba[1]);
    ans[(long)r*3+2]  = sigf(A2 + ba[2]);
    span[(long)r*2+0] = sigf(S0 + bsp[0]);
    span[(long)r*2+1] = sigf(S1 + bsp[1]);
  }
}

// ---------------------------------------------------------------- launch
extern "C" void kernel_launch(void* const* d_in, const int* in_sizes, int n_in,
                              void* d_out, int out_size, void* d_ws, size_t ws_size,
                              hipStream_t stream)
{
  const int*   input_ids = (const int*)  d_in[0];
  const float* attn_mask = (const float*)d_in[1];
  const int*   html_idx  = (const int*)  d_in[2];
  const float* embed     = (const float*)d_in[3];
  const float* Wq = (const float*)d_in[4];  const float* bq = (const float*)d_in[5];
  const float* Wk = (const float*)d_in[6];  const float* bk = (const float*)d_in[7];
  const float* Wv = (const float*)d_in[8];  const float* bv = (const float*)d_in[9];
  const float* Wo = (const float*)d_in[10]; const float* bo = (const float*)d_in[11];
  const float* gamma = (const float*)d_in[12]; const float* beta = (const float*)d_in[13];
  const float* Wp = (const float*)d_in[14]; const float* bp = (const float*)d_in[15];
  const float* Wa = (const float*)d_in[16]; const float* ba = (const float*)d_in[17];
  const float* Wsp = (const float*)d_in[18]; const float* bsp = (const float*)d_in[19];

  char* ws = (char*)d_ws;
  size_t off = 0;
  auto take = [&](size_t bytes)->char*{
    char* p = ws + off; off += (bytes + 255) & ~(size_t)255; return p;
  };
  u16*   x_b    = (u16*)  take((size_t)8192*768*2);
  u16*   wt_qkv = (u16*)  take((size_t)2304*768*2);
  u16*   wt_o   = (u16*)  take((size_t)768*768*2);
  u16*   wt_p   = (u16*)  take((size_t)768*768*2);
  float* b_qkv  = (float*)take(2304*4);
  u16*   qkv_b  = (u16*)  take((size_t)8192*2304*2);
  u16*   ctx_b  = (u16*)  take((size_t)8192*768*2);
  u16*   h_b    = (u16*)  take((size_t)8192*768*2);
  u16*   hr_b   = (u16*)  take((size_t)512*768*2);
  u16*   t_b    = (u16*)  take((size_t)512*768*2);
  float* pout   = (float*)take((size_t)KCH*BC*NH*64*64*4);
  float* pml    = (float*)take((size_t)KCH*BC*NH*128*4);

  float* out_hn   = (float*)d_out;
  float* out_ans  = out_hn  + (size_t)8192*768;
  float* out_span = out_ans + (size_t)8192*3;
  float* out_cond = out_span + (size_t)8192*2;

  pack_embed<<<6864, 256, 0, stream>>>(Wq, Wk, Wv, Wo, Wp, bq, bk, bv,
                                       wt_qkv, wt_o, wt_p, b_qkv,
                                       input_ids, embed, x_b);

  gemm_bt<0,true><<<dim3(18,64,1), 256, 0, stream>>>(x_b, wt_qkv, b_qkv, nullptr,
                                                nullptr, qkv_b, 8192, 2304, 768, 0,0,0);
  attn_band_mfma<<<dim3(64,12,2), 256, 0, stream>>>(qkv_b, attn_mask, ctx_b);
  attn_global_part<<<dim3(KCH,12,2), 256, 0, stream>>>(qkv_b, attn_mask, pout, pml);
  attn_global_combine<<<BC*NH, 256, 0, stream>>>(pout, pml, ctx_b);
  gemm_bt<1,true><<<dim3(6,64,1), 256, 0, stream>>>(ctx_b, wt_o, bo, x_b,
                                               nullptr, h_b, 8192, 768, 768, 0,0,0);
  ln_heads<<<8192, 384, 0, stream>>>(h_b, gamma, beta, Wa, ba, Wsp, bsp,
                                     out_hn, out_ans, out_span);
  gather_hr<<<1536, 256, 0, stream>>>(html_idx, out_hn, hr_b);
  gemm_bt<2,false><<<dim3(6,4,1), 256, 0, stream>>>(hr_b, wt_p, bp, nullptr,
                                              nullptr, t_b, 512, 768, 768, 0,0,0);
  gemm_bt<3,false><<<dim3(2,2,2), 256, 0, stream>>>(t_b, hr_b, nullptr, nullptr,
                                              out_cond, nullptr, 256, 256, 768,
                                              (long)256*768, (long)256*768, (long)256*256);
}